// Round 6
// baseline (380.839 us; speedup 1.0000x reference)
//
#include <hip/hip_runtime.h>
#include <math.h>

#define BB 512
#define HH 512
#define KK 6
#define TT 60
#define OO 2
#define H2 1024
#define TO 120
#define RFP 520   // padded LDS row stride (bf16 elems), 1040B = 65x16B
#define HSP 1032  // padded h row stride (bf16 elems)

typedef __bf16 bf16x8 __attribute__((ext_vector_type(8)));
typedef float  f32x4  __attribute__((ext_vector_type(4)));
typedef float  f32x16 __attribute__((ext_vector_type(16)));

__device__ __forceinline__ float bf2f(unsigned short u) {
    union { unsigned int i; float f; } v; v.i = ((unsigned int)u) << 16; return v.f;
}
__device__ __forceinline__ unsigned short f2bf(float f) {
    union { float f; unsigned int i; } v; v.f = f;
    unsigned int b = v.i;
    return (unsigned short)((b + 0x7FFFu + ((b >> 16) & 1u)) >> 16); // RNE
}
// pair-pack via HW cvt (v_cvt_pk_bf16_f32, RNE on gfx950): 1-2 inst vs ~9 int ops
__device__ __forceinline__ unsigned int pack2bf(float a, float b) {
    union { __bf16 h[2]; unsigned int u; } v;
    v.h[0] = (__bf16)a; v.h[1] = (__bf16)b;
    return v.u;
}
__device__ __forceinline__ float gelu_exact(float x) {
    return 0.5f * x * (1.0f + erff(x * 0.70710678118654752f));
}

#if defined(__has_builtin)
#  if __has_builtin(__builtin_amdgcn_rcpf)
#    define FAST_RCP(x) __builtin_amdgcn_rcpf(x)
#  endif
#  if __has_builtin(__builtin_amdgcn_exp2f)
#    define FAST_EXP2(x) __builtin_amdgcn_exp2f(x)
#  endif
#endif
#ifndef FAST_RCP
#  define FAST_RCP(x) (1.0f / (x))
#endif
#ifndef FAST_EXP2
#  define FAST_EXP2(x) __expf((x) * 0.69314718056f)
#endif

// tanh-form GELU, constants pre-scaled by log2(e); ~7 VALU inst, err ~3e-4.
__device__ __forceinline__ float gelu_cheap(float x) {
    float x2 = x * x;
    float z = x * fmaf(0.10294324f, x2, 2.3022082f);
    float e = FAST_EXP2(-z);
    return x * FAST_RCP(1.0f + e);
}

struct F8 { float v[8]; };
__device__ __forceinline__ F8 load8f(const float* p) {
    F8 r;
    float4 a = *(const float4*)p;
    float4 b = *(const float4*)(p + 4);
    r.v[0] = a.x; r.v[1] = a.y; r.v[2] = a.z; r.v[3] = a.w;
    r.v[4] = b.x; r.v[5] = b.y; r.v[6] = b.z; r.v[7] = b.w;
    return r;
}
__device__ __forceinline__ F8 load8b(const unsigned short* p) {
    ushort4 a = *(const ushort4*)p;
    ushort4 b = *(const ushort4*)(p + 4);
    F8 r;
    r.v[0] = bf2f(a.x); r.v[1] = bf2f(a.y); r.v[2] = bf2f(a.z); r.v[3] = bf2f(a.w);
    r.v[4] = bf2f(b.x); r.v[5] = bf2f(b.y); r.v[6] = bf2f(b.z); r.v[7] = bf2f(b.w);
    return r;
}

// ---- fragment-order weight pack: B-records of 512 bf16 (1KB), one wave-load each ----
// NC=16 (16x16x32 MFMA): rec[ln*8+j] = W[step*32 + (ln>>4)*8 + j][nch*16 + (ln&15)]
// NC=32 (32x32x16 MFMA): rec[ln*8+j] = W[step*16 + (ln>>5)*8 + j][nch*32 + (ln&31)]
// -> consumer load: base + (nch*steps + step)*512 + ln*8  (coalesced 1KB/wave)
struct PKD { const float* src; unsigned short* dst; int F, N, NC, nch, steps, Z; };
struct PK8 { PKD e[8]; };

__global__ void k_pack(PK8 d) {
    int rid = blockIdx.x * 4 + (threadIdx.x >> 6);
    const int ln = threadIdx.x & 63;
    int i = 0;
    while (i < 7) {
        int tot = d.e[i].Z * d.e[i].nch * d.e[i].steps;
        if (rid < tot) break;
        rid -= tot; ++i;
    }
    const PKD e = d.e[i];
    const int per = e.nch * e.steps;
    const int z = rid / per;
    const int r = rid - z * per;
    const int nch = r / e.steps, step = r - nch * e.steps;
    const float* src = e.src + (size_t)z * e.F * e.N;
    unsigned short* dst = e.dst + ((size_t)z * per + r) * 512 + ln * 8;
    int f_base, n;
    if (e.NC == 16) { f_base = step * 32 + (ln >> 4) * 8; n = nch * 16 + (ln & 15); }
    else            { f_base = step * 16 + (ln >> 5) * 8; n = nch * 32 + (ln & 31); }
    if (n >= e.N) n = e.N - 1;   // clamp (Wk2: logical 128 cols over 120 real)
    unsigned int pk[4];
#pragma unroll
    for (int j = 0; j < 4; ++j) {
        unsigned short lo = f2bf(src[(size_t)(f_base + 2 * j) * e.N + n]);
        unsigned short hi = f2bf(src[(size_t)(f_base + 2 * j + 1) * e.N + n]);
        pk[j] = (unsigned int)lo | ((unsigned int)hi << 16);
    }
    *(uint4*)dst = make_uint4(pk[0], pk[1], pk[2], pk[3]);
}

// --------- MFMA ctx-chain GEMM: C(512x512 bf16) = [gelu](A @ B + bias), packed-B ---------
template <bool CONCAT, bool GELU>
__launch_bounds__(256)
__global__ void k_gemm_m(const void* __restrict__ A0, const void* __restrict__ A1,
                         const void* __restrict__ A2, const unsigned short* __restrict__ BP,
                         const float* __restrict__ bias, unsigned short* __restrict__ C,
                         int Kd) {
    __shared__ __align__(16) unsigned short As[32 * RFP];
    const int tid = threadIdx.x;
    const int bm = blockIdx.x * 32;
    const int bn = blockIdx.y * 64;
    const int w = tid >> 6, ln = tid & 63;
    const int lane15 = ln & 15, quad = ln >> 4;
    const int n = bn + w * 16 + lane15;
    const int nchunks = Kd / HH;
    const int stepsTot = Kd / 32;
    const int nchB = blockIdx.y * 4 + w;

    f32x4 acc0 = {0.f, 0.f, 0.f, 0.f}, acc1 = {0.f, 0.f, 0.f, 0.f};

    for (int kc = 0; kc < nchunks; ++kc) {
        {
            int r = tid >> 3, c0 = (tid & 7) * 64;
            unsigned short* dp = As + r * RFP + c0;
            if (CONCAT) {
                const float* src = (kc == 0) ? (const float*)A0
                                 : (kc == 1) ? (const float*)A1 : (const float*)A2;
                const float* sp = src + (bm + r) * HH + c0;
                for (int c = 0; c < 64; c += 8) {
                    F8 v = load8f(sp + c);
                    unsigned int pk[4];
#pragma unroll
                    for (int j = 0; j < 4; ++j)
                        pk[j] = pack2bf(v.v[2 * j], v.v[2 * j + 1]);
                    *(uint4*)(dp + c) = make_uint4(pk[0], pk[1], pk[2], pk[3]);
                }
            } else {
                const unsigned short* sp = (const unsigned short*)A0 + (bm + r) * HH + c0;
                for (int c = 0; c < 64; c += 8)
                    *(uint4*)(dp + c) = *(const uint4*)(sp + c);
            }
        }
        __syncthreads();
        const unsigned short* bp = BP + ((size_t)nchB * stepsTot + kc * 16) * 512 + ln * 8;
#pragma unroll
        for (int f0 = 0; f0 < HH; f0 += 32) {
            bf16x8 a0 = *(const bf16x8*)(As + lane15 * RFP + f0 + quad * 8);
            bf16x8 a1 = *(const bf16x8*)(As + (16 + lane15) * RFP + f0 + quad * 8);
            bf16x8 bf = *(const bf16x8*)(bp);
            bp += 512;
            acc0 = __builtin_amdgcn_mfma_f32_16x16x32_bf16(a0, bf, acc0, 0, 0, 0);
            acc1 = __builtin_amdgcn_mfma_f32_16x16x32_bf16(a1, bf, acc1, 0, 0, 0);
        }
        __syncthreads();
    }
    const float bb = bias[n];
#pragma unroll
    for (int reg = 0; reg < 4; ++reg) {
        float v0 = acc0[reg] + bb, v1 = acc1[reg] + bb;
        if (GELU) { v0 = gelu_exact(v0); v1 = gelu_exact(v1); }
        C[(bm + quad * 4 + reg) * HH + n] = f2bf(v0);
        C[(bm + 16 + quad * 4 + reg) * HH + n] = f2bf(v1);
    }
}

// ---------------- k_bc: batched coarse-heads + conf, packed-B ----------------
__launch_bounds__(512)
__global__ void k_bc(const unsigned short* __restrict__ ctx, const float* __restrict__ mq,
                     const unsigned short* __restrict__ Wk1P, const float* __restrict__ bk1,
                     const unsigned short* __restrict__ Wk2P, const float* __restrict__ bk2,
                     const unsigned short* __restrict__ Wf1P, const float* __restrict__ bf1,
                     const float* __restrict__ Wf2, const float* __restrict__ bf2v,
                     unsigned short* __restrict__ coarse_out, float* __restrict__ conf_out)
{
    __shared__ __align__(16) unsigned short mf[16 * RFP];   // 16,640 B
    __shared__ __align__(16) unsigned short hs[16 * HSP];   // 33,024 B

    const int tid = threadIdx.x;
    const int k = blockIdx.x % KK;
    const int b0 = (blockIdx.x / KK) * 16;
    const int w = tid >> 6;
    const int ln = tid & 63;
    const int lane15 = ln & 15;
    const int quad = ln >> 4;

    // ---- stage mf = bf16(ctx + mq[k]) rows b0..b0+15 ----
    {
        int r = tid >> 5;               // 0..15
        int c0 = (tid & 31) * 16;
        const unsigned short* cp = ctx + (b0 + r) * HH + c0;
        const float* qp = mq + k * HH + c0;
        unsigned short* dp = mf + r * RFP + c0;
        for (int c = 0; c < 16; c += 8) {
            F8 cv = load8b(cp + c);
            F8 qv = load8f(qp + c);
            unsigned int pk[4];
#pragma unroll
            for (int j = 0; j < 4; ++j)
                pk[j] = pack2bf(cv.v[2 * j] + qv.v[2 * j], cv.v[2 * j + 1] + qv.v[2 * j + 1]);
            *(uint4*)(dp + c) = make_uint4(pk[0], pk[1], pk[2], pk[3]);
        }
    }
    __syncthreads();

    // ---- GEMM1: h = gelu(mf @ Wk1[k] + bk1[k]) -> hs. Packed-B: nch = w*8+g, 16 steps ----
    {
        const unsigned short* wk1p = Wk1P + (size_t)k * (64 * 16 * 512);
        const float* bk1p = bk1 + k * H2;
        for (int g = 0; g < 8; ++g) {
            const int n = w * 128 + g * 16 + lane15;
            f32x4 acc0 = {0.f,0.f,0.f,0.f};
            const unsigned short* bp = wk1p + (size_t)((w * 8 + g) * 16) * 512 + ln * 8;
#pragma unroll
            for (int f0 = 0; f0 < HH; f0 += 32) {
                bf16x8 a0 = *(const bf16x8*)(mf + lane15 * RFP + f0 + quad * 8);
                bf16x8 bf = *(const bf16x8*)(bp);
                bp += 512;
                acc0 = __builtin_amdgcn_mfma_f32_16x16x32_bf16(a0, bf, acc0, 0, 0, 0);
            }
            const float bias = bk1p[n];
#pragma unroll
            for (int reg = 0; reg < 4; ++reg)
                hs[(quad * 4 + reg) * HSP + n] = f2bf(gelu_exact(acc0[reg] + bias));
        }
    }
    __syncthreads();

    // ---- GEMM2: coarse = h @ Wk2[k] + bk2[k]. Packed-B: nch = w, 32 steps (clamp baked) ----
    {
        const unsigned short* wk2p = Wk2P + (size_t)k * (8 * 32 * 512);
        const int n = w * 16 + lane15;
        f32x4 acc0 = {0.f,0.f,0.f,0.f};
        const unsigned short* bp = wk2p + (size_t)(w * 32) * 512 + ln * 8;
#pragma unroll
        for (int f0 = 0; f0 < H2; f0 += 32) {
            bf16x8 a0 = *(const bf16x8*)(hs + lane15 * HSP + f0 + quad * 8);
            bf16x8 bf = *(const bf16x8*)(bp);
            bp += 512;
            acc0 = __builtin_amdgcn_mfma_f32_16x16x32_bf16(a0, bf, acc0, 0, 0, 0);
        }
        if (n < TO) {
            const float bias = bk2[k * TO + n];
#pragma unroll
            for (int reg = 0; reg < 4; ++reg)
                coarse_out[((b0 + quad * 4 + reg) * KK + k) * TO + n] = f2bf(acc0[reg] + bias);
        }
    }

    // ---- GEMM3 (wave 0): conf = relu(mf @ Wf1 + bf1) @ Wf2 + bf2. Packed-B: nch = nt ----
    if (w == 0) {
        f32x4 acc[4];
#pragma unroll
        for (int nt = 0; nt < 4; ++nt) { f32x4 z = {0.f,0.f,0.f,0.f}; acc[nt] = z; }
#pragma unroll
        for (int f0 = 0; f0 < HH; f0 += 32) {
            const int step = f0 >> 5;
            bf16x8 a0 = *(const bf16x8*)(mf + lane15 * RFP + f0 + quad * 8);
#pragma unroll
            for (int nt = 0; nt < 4; ++nt) {
                bf16x8 bf = *(const bf16x8*)(Wf1P + (size_t)(nt * 16 + step) * 512 + ln * 8);
                acc[nt] = __builtin_amdgcn_mfma_f32_16x16x32_bf16(a0, bf, acc[nt], 0, 0, 0);
            }
        }
        const float b2 = bf2v[0];
#pragma unroll
        for (int reg = 0; reg < 4; ++reg) {
            float s = 0.f;
#pragma unroll
            for (int nt = 0; nt < 4; ++nt) {
                const int n = nt * 16 + lane15;
                s = fmaf(fmaxf(acc[nt][reg] + bf1[n], 0.f), Wf2[n], s);
            }
#pragma unroll
            for (int off = 1; off < 16; off <<= 1) s += __shfl_xor(s, off);
            if (lane15 == 0)
                conf_out[(b0 + quad * 4 + reg) * KK + k] = s + b2;
        }
    }
}

// ---------------- k_ef: one block per b, 16 waves, producer/consumer specialization ----------------
// Waves 0-7 (F-waves): refine GEMM via 32x32x16 MFMA on rf[cur] (swapped operands:
// m on lanes, n in regs -> in-lane Wr2 contraction). Waves 8-15 (E-waves): traj+LN
// producer for mode k+1 into rf[cur^1]. Each SIMD hosts 2 F-waves + 2 E-waves, so
// MFMA and VALU pipes are both fed continuously (m114) and 4 waves/SIMD hide latency.
__launch_bounds__(1024, 4)
__global__ void k_ef(
    const unsigned short* __restrict__ attn, const unsigned short* __restrict__ coarse_ws,
    const float* __restrict__ Wt,  const float* __restrict__ bt,
    const float* __restrict__ lng, const float* __restrict__ lnb,
    const unsigned short* __restrict__ Wr1P, const float* __restrict__ br1,
    const float* __restrict__ Wr2, const float* __restrict__ br2,
    float* __restrict__ pred_out)
{
    __shared__ __align__(16) unsigned short rf[2][64 * RFP];  // 133,120 B
    __shared__ float  po2[2][8][64][2];                        // 8,192 B
    __shared__ float  br1d[2][HH];                             // 4,096 B
    __shared__ float2 wr2d[2][HH];                             // 8,192 B
    // total 153,600 B -> 1 block/CU, 16 waves

    const int tid = threadIdx.x;
    const int b = blockIdx.x;        // grid = BB
    const int w = tid >> 6;          // 0..15
    const int ln = tid & 63;
    const int lane31 = ln & 31;
    const int hf = ln >> 5;
    const int cbase = ln * 8;
    const int w8 = w & 7;
    const bool fwave = (w < 8);

    // E: rf[buf] = LN(gelu(coarse[b,j] @ Wt + bt) + attn_b). E-waves only.
    // Weight/LN/attn vectors reloaded per call (L2-hot) to keep live ranges short.
    auto do_E = [&](int j, int buf) {
        F8 w0 = load8f(Wt + cbase);
        F8 w1 = load8f(Wt + HH + cbase);
        F8 b8 = load8f(bt + cbase);
        F8 g8 = load8f(lng + cbase);
        F8 bb8 = load8f(lnb + cbase);
        F8 a8 = load8b(attn + b * HH + cbase);
        unsigned short* rfb = &rf[buf][0];
        const unsigned short* cw = coarse_ws + (b * KK + j) * TO;
#pragma unroll
        for (int r = 0; r < 8; ++r) {
            int t = w8 + 8 * r;
            if (t < 60) {
                unsigned int cc = *(const unsigned int*)(cw + 2 * t);
                float co0 = bf2f((unsigned short)(cc & 0xffffu));
                float co1 = bf2f((unsigned short)(cc >> 16));
                float x[8]; float s = 0.f, s2 = 0.f;
#pragma unroll
                for (int jj = 0; jj < 8; ++jj) {
                    float vv = fmaf(co0, w0.v[jj], fmaf(co1, w1.v[jj], b8.v[jj]));
                    vv = gelu_cheap(vv) + a8.v[jj];
                    x[jj] = vv; s += vv; s2 = fmaf(vv, vv, s2);
                }
#pragma unroll
                for (int off = 32; off > 0; off >>= 1) {
                    s += __shfl_xor(s, off);
                    s2 += __shfl_xor(s2, off);
                }
                float mean = s * (1.0f / HH);
                float var = fmaf(-mean, mean, s2 * (1.0f / HH));
                float inv = rsqrtf(var + 1e-5f);
                unsigned int pk[4];
#pragma unroll
                for (int jj = 0; jj < 4; ++jj) {
                    float y0 = fmaf((x[2 * jj] - mean) * inv, g8.v[2 * jj], bb8.v[2 * jj]);
                    float y1 = fmaf((x[2 * jj + 1] - mean) * inv, g8.v[2 * jj + 1], bb8.v[2 * jj + 1]);
                    pk[jj] = pack2bf(y0, y1);
                }
                *(uint4*)(rfb + t * RFP + cbase) = make_uint4(pk[0], pk[1], pk[2], pk[3]);
            } else {
                *(uint4*)(rfb + t * RFP + cbase) = make_uint4(0, 0, 0, 0);
            }
        }
    };

    // stage br1/Wr2 for mode j; called by the 512 E-wave threads
    auto do_stage_g = [&](int j, int buf) {
        int i = tid & 511;
        br1d[buf][i] = br1[j * HH + i];
        wr2d[buf][i] = ((const float2*)Wr2)[(size_t)j * HH + i];
    };

    // F: packed-B records [nch=16][step=32][512]; F-wave w8 owns nch 2*w8, 2*w8+1.
    auto do_F = [&](int kk, int buf) {
        const unsigned short* bp0 = Wr1P + (size_t)kk * (16 * 32 * 512)
                                  + (size_t)(w8 * 2) * 32 * 512 + ln * 8;
        const unsigned short* bp1 = bp0 + 32 * 512;   // next nch
        const int n0 = w8 * 64;
        const unsigned short* rfb = &rf[buf][0];
        const unsigned short* a0p = rfb + lane31 * RFP + hf * 8;
        const unsigned short* a1p = a0p + 32 * RFP;

        f32x16 acc00 = {0.f,0.f,0.f,0.f,0.f,0.f,0.f,0.f,0.f,0.f,0.f,0.f,0.f,0.f,0.f,0.f};
        f32x16 acc01 = acc00, acc10 = acc00, acc11 = acc00;

        __builtin_amdgcn_s_setprio(1);
#pragma unroll
        for (int st = 0; st < 32; ++st) {
            const int k0 = st * 16;
            bf16x8 A0 = *(const bf16x8*)(a0p + k0);
            bf16x8 A1 = *(const bf16x8*)(a1p + k0);
            bf16x8 B0 = *(const bf16x8*)(bp0 + st * 512);
            bf16x8 B1 = *(const bf16x8*)(bp1 + st * 512);
            acc00 = __builtin_amdgcn_mfma_f32_32x32x16_bf16(B0, A0, acc00, 0, 0, 0);
            acc01 = __builtin_amdgcn_mfma_f32_32x32x16_bf16(B1, A0, acc01, 0, 0, 0);
            acc10 = __builtin_amdgcn_mfma_f32_32x32x16_bf16(B0, A1, acc10, 0, 0, 0);
            acc11 = __builtin_amdgcn_mfma_f32_32x32x16_bf16(B1, A1, acc11, 0, 0, 0);
        }
        __builtin_amdgcn_s_setprio(0);

        float p00 = 0.f, p01 = 0.f, p10 = 0.f, p11 = 0.f;  // [m-half][o]
#pragma unroll
        for (int nt = 0; nt < 2; ++nt) {
#pragma unroll
            for (int reg = 0; reg < 16; ++reg) {
                const int n = n0 + nt * 32 + (reg & 3) + 8 * (reg >> 2) + 4 * hf;
                const float bb = br1d[buf][n];
                const float2 w2 = wr2d[buf][n];
                const float a0v = nt ? acc01[reg] : acc00[reg];
                const float a1v = nt ? acc11[reg] : acc10[reg];
                const float rv0 = gelu_cheap(a0v + bb);
                const float rv1 = gelu_cheap(a1v + bb);
                p00 = fmaf(rv0, w2.x, p00);
                p01 = fmaf(rv0, w2.y, p01);
                p10 = fmaf(rv1, w2.x, p10);
                p11 = fmaf(rv1, w2.y, p11);
            }
        }
        p00 += __shfl_xor(p00, 32);
        p01 += __shfl_xor(p01, 32);
        p10 += __shfl_xor(p10, 32);
        p11 += __shfl_xor(p11, 32);
        if (ln < 32) {
            *(float2*)&po2[buf][w8][lane31][0]      = make_float2(p00, p01);
            *(float2*)&po2[buf][w8][32 + lane31][0] = make_float2(p10, p11);
        }
    };

    auto do_pred = [&](int kk, int buf) {
        if (tid < TO) {
            int t = tid >> 1, o = tid & 1;
            float s = 0.f;
#pragma unroll
            for (int ww = 0; ww < 8; ++ww) s += po2[buf][ww][t][o];
            float co = bf2f(coarse_ws[(b * KK + kk) * TO + tid]);
            pred_out[((b * KK + kk) * TT + t) * 2 + o] = co + s + br2[kk * 2 + o];
        }
    };

    // ---- prologue: E-waves stage + produce mode 0 ----
    if (!fwave) {
        do_stage_g(0, 0);
        do_E(0, 0);
    }
    __syncthreads();

    // ---- k-loop: F-waves consume rf[cur]; E-waves produce rf[cur^1] ----
    for (int kk = 0; kk < KK; ++kk) {
        const int cur = kk & 1;
        if (fwave) {
            do_F(kk, cur);
        } else if (kk < KK - 1) {
            do_stage_g(kk + 1, cur ^ 1);
            do_E(kk + 1, cur ^ 1);
        }
        __syncthreads();
        do_pred(kk, cur);
    }
}

// ---------------- softmax over K for mode_probs ----------------
__global__ void k_softmax(const float* __restrict__ conf, float* __restrict__ out) {
    int b = blockIdx.x * blockDim.x + threadIdx.x;
    if (b < BB) {
        float v[KK];
        float m = -1e30f;
        for (int i = 0; i < KK; ++i) { v[i] = conf[b * KK + i]; m = fmaxf(m, v[i]); }
        float s = 0.f;
        for (int i = 0; i < KK; ++i) { v[i] = __expf(v[i] - m); s += v[i]; }
        float inv = 1.0f / s;
        for (int i = 0; i < KK; ++i) out[b * KK + i] = v[i] * inv;
    }
}

extern "C" void kernel_launch(void* const* d_in, const int* in_sizes, int n_in,
                              void* d_out, int out_size, void* d_ws, size_t ws_size,
                              hipStream_t stream) {
    const float* I0  = (const float*)d_in[0];
    const float* I1  = (const float*)d_in[1];
    const float* I2  = (const float*)d_in[2];
    const float* MQ  = (const float*)d_in[3];
    const float* Wc1 = (const float*)d_in[4];
    const float* bc1 = (const float*)d_in[5];
    const float* Wc2 = (const float*)d_in[6];
    const float* bc2 = (const float*)d_in[7];
    const float* Wk1 = (const float*)d_in[8];
    const float* bk1 = (const float*)d_in[9];
    const float* Wk2 = (const float*)d_in[10];
    const float* bk2 = (const float*)d_in[11];
    const float* Wt  = (const float*)d_in[12];
    const float* bt  = (const float*)d_in[13];
    const float* Wv  = (const float*)d_in[18];
    const float* bv  = (const float*)d_in[19];
    const float* Wo  = (const float*)d_in[20];
    const float* bo  = (const float*)d_in[21];
    const float* lng = (const float*)d_in[22];
    const float* lnb = (const float*)d_in[23];
    const float* Wr1 = (const float*)d_in[24];
    const float* br1 = (const float*)d_in[25];
    const float* Wr2 = (const float*)d_in[26];
    const float* br2 = (const float*)d_in[27];
    const float* Wf1 = (const float*)d_in[28];
    const float* bf1 = (const float*)d_in[29];
    const float* Wf2 = (const float*)d_in[30];
    const float* bf2v = (const float*)d_in[31];

    // workspace layout (bf16 elems)
    unsigned short* wsu   = (unsigned short*)d_ws;
    unsigned short* wc1p  = wsu;                 //   786,432  (32nch x 48st x 512)
    unsigned short* wc2p  = wsu + 786432;        //   262,144
    unsigned short* wvp   = wsu + 1048576;       //   262,144
    unsigned short* wop   = wsu + 1310720;       //   262,144
    unsigned short* wk1p  = wsu + 1572864;       // 3,145,728  (K x 64nch x 16st x 512)
    unsigned short* wk2p  = wsu + 4718592;       //   786,432  (K x 8nch x 32st x 512, clamped)
    unsigned short* wf1p  = wsu + 5505024;       //    32,768  (4nch x 16st x 512)
    unsigned short* wr1p  = wsu + 5537792;       // 1,572,864  (K x 16nch x 32st x 512)
    unsigned short* ctx   = wsu + 7110656;       //   262,144
    unsigned short* attn  = wsu + 7372800;       //   262,144
    unsigned short* tmp   = wsu + 7634944;       //   262,144
    unsigned short* coarse= wsu + 7897088;       //   368,640
    float* conf = (float*)(wsu + 8265728);       //     3,072 fp32

    float* pred = (float*)d_out;
    float* probs = pred + BB * KK * TT * OO;

    // -- prep: all GEMM B-weights -> bf16 fragment-order records, one launch --
    PK8 pk;
    pk.e[0] = {Wc1, wc1p, 3 * HH, HH, 16, 32, 48, 1};   // 1536 recs
    pk.e[1] = {Wc2, wc2p, HH, HH, 16, 32, 16, 1};       //  512
    pk.e[2] = {Wv,  wvp,  HH, HH, 16, 32, 16, 1};       //  512
    pk.e[3] = {Wo,  wop,  HH, HH, 16, 32, 16, 1};       //  512
    pk.e[4] = {Wk1, wk1p, HH, H2, 16, 64, 16, KK};      // 6144
    pk.e[5] = {Wk2, wk2p, H2, TO, 16, 8, 32, KK};       // 1536 (clamped cols)
    pk.e[6] = {Wf1, wf1p, HH, 64, 16, 4, 16, 1};        //   64
    pk.e[7] = {Wr1, wr1p, HH, HH, 32, 16, 32, KK};      // 3072
    // total 13,888 records; 4 records (waves) per 256-thread block
    k_pack<<<dim3(3472), 256, 0, stream>>>(pk);

    // -- ctx chain --
    k_gemm_m<true,  true ><<<dim3(16, 8), 256, 0, stream>>>(I0, I1, I2, wc1p, bc1, tmp, 3 * HH);
    k_gemm_m<false, false><<<dim3(16, 8), 256, 0, stream>>>(tmp, nullptr, nullptr, wc2p, bc2, ctx, HH);
    k_gemm_m<false, false><<<dim3(16, 8), 256, 0, stream>>>(ctx, nullptr, nullptr, wvp, bv, tmp, HH);
    k_gemm_m<false, false><<<dim3(16, 8), 256, 0, stream>>>(tmp, nullptr, nullptr, wop, bo, attn, HH);

    k_bc<<<dim3(192), 512, 0, stream>>>(ctx, MQ, wk1p, bk1, wk2p, bk2, wf1p, bf1, Wf2, bf2v,
                                        coarse, conf);
    k_ef<<<dim3(BB), 1024, 0, stream>>>(attn, coarse, Wt, bt, lng, lnb,
                                        wr1p, br1, Wr2, br2, pred);
    k_softmax<<<dim3(2), 256, 0, stream>>>(conf, probs);
}

// Round 7
// 330.720 us; speedup vs baseline: 1.1515x; 1.1515x over previous
//
#include <hip/hip_runtime.h>
#include <math.h>

#define BB 512
#define HH 512
#define KK 6
#define TT 60
#define OO 2
#define H2 1024
#define TO 120
#define RFP 520   // padded LDS row stride (bf16 elems), 1040B = 65x16B
#define HSP 1032  // padded h row stride (bf16 elems)

typedef __bf16 bf16x8 __attribute__((ext_vector_type(8)));
typedef float  f32x4  __attribute__((ext_vector_type(4)));
typedef float  f32x16 __attribute__((ext_vector_type(16)));

__device__ __forceinline__ float bf2f(unsigned short u) {
    union { unsigned int i; float f; } v; v.i = ((unsigned int)u) << 16; return v.f;
}
__device__ __forceinline__ unsigned short f2bf(float f) {
    union { float f; unsigned int i; } v; v.f = f;
    unsigned int b = v.i;
    return (unsigned short)((b + 0x7FFFu + ((b >> 16) & 1u)) >> 16); // RNE
}
// pair-pack via HW cvt (v_cvt_pk_bf16_f32, RNE on gfx950): 1-2 inst vs ~9 int ops
__device__ __forceinline__ unsigned int pack2bf(float a, float b) {
    union { __bf16 h[2]; unsigned int u; } v;
    v.h[0] = (__bf16)a; v.h[1] = (__bf16)b;
    return v.u;
}
__device__ __forceinline__ float gelu_exact(float x) {
    return 0.5f * x * (1.0f + erff(x * 0.70710678118654752f));
}

#if defined(__has_builtin)
#  if __has_builtin(__builtin_amdgcn_rcpf)
#    define FAST_RCP(x) __builtin_amdgcn_rcpf(x)
#  endif
#  if __has_builtin(__builtin_amdgcn_exp2f)
#    define FAST_EXP2(x) __builtin_amdgcn_exp2f(x)
#  endif
#endif
#ifndef FAST_RCP
#  define FAST_RCP(x) (1.0f / (x))
#endif
#ifndef FAST_EXP2
#  define FAST_EXP2(x) __expf((x) * 0.69314718056f)
#endif

// tanh-form GELU, constants pre-scaled by log2(e); ~7 VALU inst, err ~3e-4.
__device__ __forceinline__ float gelu_cheap(float x) {
    float x2 = x * x;
    float z = x * fmaf(0.10294324f, x2, 2.3022082f);
    float e = FAST_EXP2(-z);
    return x * FAST_RCP(1.0f + e);
}

struct F8 { float v[8]; };
__device__ __forceinline__ F8 load8f(const float* p) {
    F8 r;
    float4 a = *(const float4*)p;
    float4 b = *(const float4*)(p + 4);
    r.v[0] = a.x; r.v[1] = a.y; r.v[2] = a.z; r.v[3] = a.w;
    r.v[4] = b.x; r.v[5] = b.y; r.v[6] = b.z; r.v[7] = b.w;
    return r;
}
__device__ __forceinline__ F8 load8b(const unsigned short* p) {
    ushort4 a = *(const ushort4*)p;
    ushort4 b = *(const ushort4*)(p + 4);
    F8 r;
    r.v[0] = bf2f(a.x); r.v[1] = bf2f(a.y); r.v[2] = bf2f(a.z); r.v[3] = bf2f(a.w);
    r.v[4] = bf2f(b.x); r.v[5] = bf2f(b.y); r.v[6] = bf2f(b.z); r.v[7] = bf2f(b.w);
    return r;
}

// ---- fragment-order weight pack: B-records of 512 bf16 (1KB), one wave-load each ----
// NC=16 (16x16x32 MFMA): rec[ln*8+j] = W[step*32 + (ln>>4)*8 + j][nch*16 + (ln&15)]
// NC=32 (32x32x16 MFMA): rec[ln*8+j] = W[step*16 + (ln>>5)*8 + j][nch*32 + (ln&31)]
// -> consumer load: base + (nch*steps + step)*512 + ln*8  (coalesced 1KB/wave)
struct PKD { const float* src; unsigned short* dst; int F, N, NC, nch, steps, Z; };
struct PK8 { PKD e[8]; };

__global__ void k_pack(PK8 d) {
    int rid = blockIdx.x * 4 + (threadIdx.x >> 6);
    const int ln = threadIdx.x & 63;
    int i = 0;
    while (i < 7) {
        int tot = d.e[i].Z * d.e[i].nch * d.e[i].steps;
        if (rid < tot) break;
        rid -= tot; ++i;
    }
    const PKD e = d.e[i];
    const int per = e.nch * e.steps;
    const int z = rid / per;
    const int r = rid - z * per;
    const int nch = r / e.steps, step = r - nch * e.steps;
    const float* src = e.src + (size_t)z * e.F * e.N;
    unsigned short* dst = e.dst + ((size_t)z * per + r) * 512 + ln * 8;
    int f_base, n;
    if (e.NC == 16) { f_base = step * 32 + (ln >> 4) * 8; n = nch * 16 + (ln & 15); }
    else            { f_base = step * 16 + (ln >> 5) * 8; n = nch * 32 + (ln & 31); }
    if (n >= e.N) n = e.N - 1;   // clamp (Wk2: logical 128 cols over 120 real)
    unsigned int pk[4];
#pragma unroll
    for (int j = 0; j < 4; ++j) {
        unsigned short lo = f2bf(src[(size_t)(f_base + 2 * j) * e.N + n]);
        unsigned short hi = f2bf(src[(size_t)(f_base + 2 * j + 1) * e.N + n]);
        pk[j] = (unsigned int)lo | ((unsigned int)hi << 16);
    }
    *(uint4*)dst = make_uint4(pk[0], pk[1], pk[2], pk[3]);
}

// --------- MFMA ctx-chain GEMM: C(512x512 bf16) = [gelu](A @ B + bias), packed-B ---------
template <bool CONCAT, bool GELU>
__launch_bounds__(256)
__global__ void k_gemm_m(const void* __restrict__ A0, const void* __restrict__ A1,
                         const void* __restrict__ A2, const unsigned short* __restrict__ BP,
                         const float* __restrict__ bias, unsigned short* __restrict__ C,
                         int Kd) {
    __shared__ __align__(16) unsigned short As[32 * RFP];
    const int tid = threadIdx.x;
    const int bm = blockIdx.x * 32;
    const int bn = blockIdx.y * 64;
    const int w = tid >> 6, ln = tid & 63;
    const int lane15 = ln & 15, quad = ln >> 4;
    const int n = bn + w * 16 + lane15;
    const int nchunks = Kd / HH;
    const int stepsTot = Kd / 32;
    const int nchB = blockIdx.y * 4 + w;

    f32x4 acc0 = {0.f, 0.f, 0.f, 0.f}, acc1 = {0.f, 0.f, 0.f, 0.f};

    for (int kc = 0; kc < nchunks; ++kc) {
        {
            int r = tid >> 3, c0 = (tid & 7) * 64;
            unsigned short* dp = As + r * RFP + c0;
            if (CONCAT) {
                const float* src = (kc == 0) ? (const float*)A0
                                 : (kc == 1) ? (const float*)A1 : (const float*)A2;
                const float* sp = src + (bm + r) * HH + c0;
                for (int c = 0; c < 64; c += 8) {
                    F8 v = load8f(sp + c);
                    unsigned int pk[4];
#pragma unroll
                    for (int j = 0; j < 4; ++j)
                        pk[j] = pack2bf(v.v[2 * j], v.v[2 * j + 1]);
                    *(uint4*)(dp + c) = make_uint4(pk[0], pk[1], pk[2], pk[3]);
                }
            } else {
                const unsigned short* sp = (const unsigned short*)A0 + (bm + r) * HH + c0;
                for (int c = 0; c < 64; c += 8)
                    *(uint4*)(dp + c) = *(const uint4*)(sp + c);
            }
        }
        __syncthreads();
        const unsigned short* bp = BP + ((size_t)nchB * stepsTot + kc * 16) * 512 + ln * 8;
#pragma unroll
        for (int f0 = 0; f0 < HH; f0 += 32) {
            bf16x8 a0 = *(const bf16x8*)(As + lane15 * RFP + f0 + quad * 8);
            bf16x8 a1 = *(const bf16x8*)(As + (16 + lane15) * RFP + f0 + quad * 8);
            bf16x8 bf = *(const bf16x8*)(bp);
            bp += 512;
            acc0 = __builtin_amdgcn_mfma_f32_16x16x32_bf16(a0, bf, acc0, 0, 0, 0);
            acc1 = __builtin_amdgcn_mfma_f32_16x16x32_bf16(a1, bf, acc1, 0, 0, 0);
        }
        __syncthreads();
    }
    const float bb = bias[n];
#pragma unroll
    for (int reg = 0; reg < 4; ++reg) {
        float v0 = acc0[reg] + bb, v1 = acc1[reg] + bb;
        if (GELU) { v0 = gelu_exact(v0); v1 = gelu_exact(v1); }
        C[(bm + quad * 4 + reg) * HH + n] = f2bf(v0);
        C[(bm + 16 + quad * 4 + reg) * HH + n] = f2bf(v1);
    }
}

// ---------------- k_bc: batched coarse-heads + conf, packed-B ----------------
__launch_bounds__(512)
__global__ void k_bc(const unsigned short* __restrict__ ctx, const float* __restrict__ mq,
                     const unsigned short* __restrict__ Wk1P, const float* __restrict__ bk1,
                     const unsigned short* __restrict__ Wk2P, const float* __restrict__ bk2,
                     const unsigned short* __restrict__ Wf1P, const float* __restrict__ bf1,
                     const float* __restrict__ Wf2, const float* __restrict__ bf2v,
                     unsigned short* __restrict__ coarse_out, float* __restrict__ conf_out)
{
    __shared__ __align__(16) unsigned short mf[16 * RFP];   // 16,640 B
    __shared__ __align__(16) unsigned short hs[16 * HSP];   // 33,024 B

    const int tid = threadIdx.x;
    const int k = blockIdx.x % KK;
    const int b0 = (blockIdx.x / KK) * 16;
    const int w = tid >> 6;
    const int ln = tid & 63;
    const int lane15 = ln & 15;
    const int quad = ln >> 4;

    // ---- stage mf = bf16(ctx + mq[k]) rows b0..b0+15 ----
    {
        int r = tid >> 5;               // 0..15
        int c0 = (tid & 31) * 16;
        const unsigned short* cp = ctx + (b0 + r) * HH + c0;
        const float* qp = mq + k * HH + c0;
        unsigned short* dp = mf + r * RFP + c0;
        for (int c = 0; c < 16; c += 8) {
            F8 cv = load8b(cp + c);
            F8 qv = load8f(qp + c);
            unsigned int pk[4];
#pragma unroll
            for (int j = 0; j < 4; ++j)
                pk[j] = pack2bf(cv.v[2 * j] + qv.v[2 * j], cv.v[2 * j + 1] + qv.v[2 * j + 1]);
            *(uint4*)(dp + c) = make_uint4(pk[0], pk[1], pk[2], pk[3]);
        }
    }
    __syncthreads();

    // ---- GEMM1: h = gelu(mf @ Wk1[k] + bk1[k]) -> hs. Packed-B: nch = w*8+g, 16 steps ----
    {
        const unsigned short* wk1p = Wk1P + (size_t)k * (64 * 16 * 512);
        const float* bk1p = bk1 + k * H2;
        for (int g = 0; g < 8; ++g) {
            const int n = w * 128 + g * 16 + lane15;
            f32x4 acc0 = {0.f,0.f,0.f,0.f};
            const unsigned short* bp = wk1p + (size_t)((w * 8 + g) * 16) * 512 + ln * 8;
#pragma unroll
            for (int f0 = 0; f0 < HH; f0 += 32) {
                bf16x8 a0 = *(const bf16x8*)(mf + lane15 * RFP + f0 + quad * 8);
                bf16x8 bf = *(const bf16x8*)(bp);
                bp += 512;
                acc0 = __builtin_amdgcn_mfma_f32_16x16x32_bf16(a0, bf, acc0, 0, 0, 0);
            }
            const float bias = bk1p[n];
#pragma unroll
            for (int reg = 0; reg < 4; ++reg)
                hs[(quad * 4 + reg) * HSP + n] = f2bf(gelu_exact(acc0[reg] + bias));
        }
    }
    __syncthreads();

    // ---- GEMM2: coarse = h @ Wk2[k] + bk2[k]. Packed-B: nch = w, 32 steps (clamp baked) ----
    {
        const unsigned short* wk2p = Wk2P + (size_t)k * (8 * 32 * 512);
        const int n = w * 16 + lane15;
        f32x4 acc0 = {0.f,0.f,0.f,0.f};
        const unsigned short* bp = wk2p + (size_t)(w * 32) * 512 + ln * 8;
#pragma unroll
        for (int f0 = 0; f0 < H2; f0 += 32) {
            bf16x8 a0 = *(const bf16x8*)(hs + lane15 * HSP + f0 + quad * 8);
            bf16x8 bf = *(const bf16x8*)(bp);
            bp += 512;
            acc0 = __builtin_amdgcn_mfma_f32_16x16x32_bf16(a0, bf, acc0, 0, 0, 0);
        }
        if (n < TO) {
            const float bias = bk2[k * TO + n];
#pragma unroll
            for (int reg = 0; reg < 4; ++reg)
                coarse_out[((b0 + quad * 4 + reg) * KK + k) * TO + n] = f2bf(acc0[reg] + bias);
        }
    }

    // ---- GEMM3 (wave 0): conf = relu(mf @ Wf1 + bf1) @ Wf2 + bf2. Packed-B: nch = nt ----
    if (w == 0) {
        f32x4 acc[4];
#pragma unroll
        for (int nt = 0; nt < 4; ++nt) { f32x4 z = {0.f,0.f,0.f,0.f}; acc[nt] = z; }
#pragma unroll
        for (int f0 = 0; f0 < HH; f0 += 32) {
            const int step = f0 >> 5;
            bf16x8 a0 = *(const bf16x8*)(mf + lane15 * RFP + f0 + quad * 8);
#pragma unroll
            for (int nt = 0; nt < 4; ++nt) {
                bf16x8 bf = *(const bf16x8*)(Wf1P + (size_t)(nt * 16 + step) * 512 + ln * 8);
                acc[nt] = __builtin_amdgcn_mfma_f32_16x16x32_bf16(a0, bf, acc[nt], 0, 0, 0);
            }
        }
        const float b2 = bf2v[0];
#pragma unroll
        for (int reg = 0; reg < 4; ++reg) {
            float s = 0.f;
#pragma unroll
            for (int nt = 0; nt < 4; ++nt) {
                const int n = nt * 16 + lane15;
                s = fmaf(fmaxf(acc[nt][reg] + bf1[n], 0.f), Wf2[n], s);
            }
#pragma unroll
            for (int off = 1; off < 16; off <<= 1) s += __shfl_xor(s, off);
            if (lane15 == 0)
                conf_out[(b0 + quad * 4 + reg) * KK + k] = s + b2;
        }
    }
}

// ---------------- k_ef: per (b,k) block, 8 waves, packed-B, 2 blocks/CU ----------------
// E and F are sequential per wave (no register-role collision: arch peak in E,
// acc peak in F). Cross-block de-phasing (2 independent blocks/CU = 4 waves/SIMD)
// supplies MFMA||VALU overlap without wave specialization (m114).
__launch_bounds__(512, 4)
__global__ void k_ef(
    const unsigned short* __restrict__ attn, const unsigned short* __restrict__ coarse_ws,
    const float* __restrict__ Wt,  const float* __restrict__ bt,
    const float* __restrict__ lng, const float* __restrict__ lnb,
    const unsigned short* __restrict__ Wr1P, const float* __restrict__ br1,
    const float* __restrict__ Wr2, const float* __restrict__ br2,
    float* __restrict__ pred_out)
{
    __shared__ __align__(16) unsigned short rf[64 * RFP];  // 66,560 B
    __shared__ float coarse[TO];                           // 480 B
    __shared__ float br1s[HH];                             // 2,048 B
    __shared__ float2 wr2s[HH];                            // 4,096 B
    __shared__ float po2[8][64][2];                        // 4,096 B
    // total 77,280 B -> 2 blocks/CU

    const int tid = threadIdx.x;
    const int b = blockIdx.x / KK;
    const int k = blockIdx.x % KK;
    const int w = tid >> 6;          // 0..7
    const int ln = tid & 63;
    const int lane31 = ln & 31;
    const int hf = ln >> 5;
    const int cbase = ln * 8;

    const unsigned short* attb = attn + b * HH;

    if (tid < TO) coarse[tid] = bf2f(coarse_ws[(b * KK + k) * TO + tid]);
    br1s[tid] = br1[k * HH + tid];
    wr2s[tid] = ((const float2*)Wr2)[(size_t)k * HH + tid];
    __syncthreads();

    // ---- Phase E: traj=gelu(coarse@Wt+bt); rf = LN(traj+attn)*g+b (bf16) ----
    {
        F8 w0 = load8f(Wt + cbase);
        F8 w1 = load8f(Wt + HH + cbase);
        F8 b8 = load8f(bt + cbase);
        F8 g8 = load8f(lng + cbase);
        F8 bb8 = load8f(lnb + cbase);
        F8 a8 = load8b(attb + cbase);
#pragma unroll
        for (int r = 0; r < 8; ++r) {
            int t = w + 8 * r;
            if (t < 60) {
                float co0 = coarse[2 * t], co1 = coarse[2 * t + 1];
                float x[8]; float s = 0.f, s2 = 0.f;
#pragma unroll
                for (int j = 0; j < 8; ++j) {
                    float vv = fmaf(co0, w0.v[j], fmaf(co1, w1.v[j], b8.v[j]));
                    vv = gelu_cheap(vv) + a8.v[j];
                    x[j] = vv; s += vv; s2 = fmaf(vv, vv, s2);
                }
#pragma unroll
                for (int off = 32; off > 0; off >>= 1) {
                    s += __shfl_xor(s, off);
                    s2 += __shfl_xor(s2, off);
                }
                float mean = s * (1.0f / HH);
                float var = fmaf(-mean, mean, s2 * (1.0f / HH));
                float inv = rsqrtf(var + 1e-5f);
                unsigned int pk[4];
#pragma unroll
                for (int j = 0; j < 4; ++j) {
                    float y0 = fmaf((x[2 * j] - mean) * inv, g8.v[2 * j], bb8.v[2 * j]);
                    float y1 = fmaf((x[2 * j + 1] - mean) * inv, g8.v[2 * j + 1], bb8.v[2 * j + 1]);
                    pk[j] = pack2bf(y0, y1);
                }
                *(uint4*)(rf + t * RFP + cbase) = make_uint4(pk[0], pk[1], pk[2], pk[3]);
            } else {
                *(uint4*)(rf + t * RFP + cbase) = make_uint4(0, 0, 0, 0);
            }
        }
    }
    __syncthreads();

    // ---- Phase F: r=gelu(rf@Wr1+br1); offsets=r@Wr2 (32x32x16 MFMA, swapped operands,
    //      packed-B records [nch=16][step=32][512]; wave w owns nch 2w, 2w+1) ----
    {
        const unsigned short* bp0 = Wr1P + (size_t)k * (16 * 32 * 512)
                                  + (size_t)(w * 2) * 32 * 512 + ln * 8;
        const unsigned short* bp1 = bp0 + 32 * 512;   // next nch
        const int n0 = w * 64;
        const unsigned short* a0p = rf + lane31 * RFP + hf * 8;
        const unsigned short* a1p = a0p + 32 * RFP;

        f32x16 acc00 = {0.f,0.f,0.f,0.f,0.f,0.f,0.f,0.f,0.f,0.f,0.f,0.f,0.f,0.f,0.f,0.f};
        f32x16 acc01 = acc00, acc10 = acc00, acc11 = acc00;

        __builtin_amdgcn_s_setprio(1);
#pragma unroll
        for (int st = 0; st < 32; ++st) {
            const int k0 = st * 16;
            bf16x8 A0 = *(const bf16x8*)(a0p + k0);
            bf16x8 A1 = *(const bf16x8*)(a1p + k0);
            bf16x8 B0 = *(const bf16x8*)(bp0 + st * 512);
            bf16x8 B1 = *(const bf16x8*)(bp1 + st * 512);
            acc00 = __builtin_amdgcn_mfma_f32_32x32x16_bf16(B0, A0, acc00, 0, 0, 0);
            acc01 = __builtin_amdgcn_mfma_f32_32x32x16_bf16(B1, A0, acc01, 0, 0, 0);
            acc10 = __builtin_amdgcn_mfma_f32_32x32x16_bf16(B0, A1, acc10, 0, 0, 0);
            acc11 = __builtin_amdgcn_mfma_f32_32x32x16_bf16(B1, A1, acc11, 0, 0, 0);
        }
        __builtin_amdgcn_s_setprio(0);

        // In-lane contraction over n (regs); lane = m (time-step).
        float p00 = 0.f, p01 = 0.f, p10 = 0.f, p11 = 0.f;  // [m-half][o]
#pragma unroll
        for (int nt = 0; nt < 2; ++nt) {
#pragma unroll
            for (int reg = 0; reg < 16; ++reg) {
                const int n = n0 + nt * 32 + (reg & 3) + 8 * (reg >> 2) + 4 * hf;
                const float bb = br1s[n];
                const float2 w2 = wr2s[n];
                const float a0v = nt ? acc01[reg] : acc00[reg];
                const float a1v = nt ? acc11[reg] : acc10[reg];
                const float rv0 = gelu_cheap(a0v + bb);
                const float rv1 = gelu_cheap(a1v + bb);
                p00 = fmaf(rv0, w2.x, p00);
                p01 = fmaf(rv0, w2.y, p01);
                p10 = fmaf(rv1, w2.x, p10);
                p11 = fmaf(rv1, w2.y, p11);
            }
        }
        p00 += __shfl_xor(p00, 32);
        p01 += __shfl_xor(p01, 32);
        p10 += __shfl_xor(p10, 32);
        p11 += __shfl_xor(p11, 32);
        if (ln < 32) {
            *(float2*)&po2[w][lane31][0]      = make_float2(p00, p01);
            *(float2*)&po2[w][32 + lane31][0] = make_float2(p10, p11);
        }
    }
    __syncthreads();

    if (tid < TO) {
        int t = tid >> 1, o = tid & 1;
        float s = 0.f;
#pragma unroll
        for (int ww = 0; ww < 8; ++ww) s += po2[ww][t][o];
        pred_out[((b * KK + k) * TT + t) * 2 + o] = coarse[tid] + s + br2[k * 2 + o];
    }
}

// ---------------- softmax over K for mode_probs ----------------
__global__ void k_softmax(const float* __restrict__ conf, float* __restrict__ out) {
    int b = blockIdx.x * blockDim.x + threadIdx.x;
    if (b < BB) {
        float v[KK];
        float m = -1e30f;
        for (int i = 0; i < KK; ++i) { v[i] = conf[b * KK + i]; m = fmaxf(m, v[i]); }
        float s = 0.f;
        for (int i = 0; i < KK; ++i) { v[i] = __expf(v[i] - m); s += v[i]; }
        float inv = 1.0f / s;
        for (int i = 0; i < KK; ++i) out[b * KK + i] = v[i] * inv;
    }
}

extern "C" void kernel_launch(void* const* d_in, const int* in_sizes, int n_in,
                              void* d_out, int out_size, void* d_ws, size_t ws_size,
                              hipStream_t stream) {
    const float* I0  = (const float*)d_in[0];
    const float* I1  = (const float*)d_in[1];
    const float* I2  = (const float*)d_in[2];
    const float* MQ  = (const float*)d_in[3];
    const float* Wc1 = (const float*)d_in[4];
    const float* bc1 = (const float*)d_in[5];
    const float* Wc2 = (const float*)d_in[6];
    const float* bc2 = (const float*)d_in[7];
    const float* Wk1 = (const float*)d_in[8];
    const float* bk1 = (const float*)d_in[9];
    const float* Wk2 = (const float*)d_in[10];
    const float* bk2 = (const float*)d_in[11];
    const float* Wt  = (const float*)d_in[12];
    const float* bt  = (const float*)d_in[13];
    const float* Wv  = (const float*)d_in[18];
    const float* bv  = (const float*)d_in[19];
    const float* Wo  = (const float*)d_in[20];
    const float* bo  = (const float*)d_in[21];
    const float* lng = (const float*)d_in[22];
    const float* lnb = (const float*)d_in[23];
    const float* Wr1 = (const float*)d_in[24];
    const float* br1 = (const float*)d_in[25];
    const float* Wr2 = (const float*)d_in[26];
    const float* br2 = (const float*)d_in[27];
    const float* Wf1 = (const float*)d_in[28];
    const float* bf1 = (const float*)d_in[29];
    const float* Wf2 = (const float*)d_in[30];
    const float* bf2v = (const float*)d_in[31];

    // workspace layout (bf16 elems)
    unsigned short* wsu   = (unsigned short*)d_ws;
    unsigned short* wc1p  = wsu;                 //   786,432  (32nch x 48st x 512)
    unsigned short* wc2p  = wsu + 786432;        //   262,144
    unsigned short* wvp   = wsu + 1048576;       //   262,144
    unsigned short* wop   = wsu + 1310720;       //   262,144
    unsigned short* wk1p  = wsu + 1572864;       // 3,145,728  (K x 64nch x 16st x 512)
    unsigned short* wk2p  = wsu + 4718592;       //   786,432  (K x 8nch x 32st x 512, clamped)
    unsigned short* wf1p  = wsu + 5505024;       //    32,768  (4nch x 16st x 512)
    unsigned short* wr1p  = wsu + 5537792;       // 1,572,864  (K x 16nch x 32st x 512)
    unsigned short* ctx   = wsu + 7110656;       //   262,144
    unsigned short* attn  = wsu + 7372800;       //   262,144
    unsigned short* tmp   = wsu + 7634944;       //   262,144
    unsigned short* coarse= wsu + 7897088;       //   368,640
    float* conf = (float*)(wsu + 8265728);       //     3,072 fp32

    float* pred = (float*)d_out;
    float* probs = pred + BB * KK * TT * OO;

    // -- prep: all GEMM B-weights -> bf16 fragment-order records, one launch --
    PK8 pk;
    pk.e[0] = {Wc1, wc1p, 3 * HH, HH, 16, 32, 48, 1};   // 1536 recs
    pk.e[1] = {Wc2, wc2p, HH, HH, 16, 32, 16, 1};       //  512
    pk.e[2] = {Wv,  wvp,  HH, HH, 16, 32, 16, 1};       //  512
    pk.e[3] = {Wo,  wop,  HH, HH, 16, 32, 16, 1};       //  512
    pk.e[4] = {Wk1, wk1p, HH, H2, 16, 64, 16, KK};      // 6144
    pk.e[5] = {Wk2, wk2p, H2, TO, 16, 8, 32, KK};       // 1536 (clamped cols)
    pk.e[6] = {Wf1, wf1p, HH, 64, 16, 4, 16, 1};        //   64
    pk.e[7] = {Wr1, wr1p, HH, HH, 32, 16, 32, KK};      // 3072
    // total 13,888 records; 4 records (waves) per 256-thread block
    k_pack<<<dim3(3472), 256, 0, stream>>>(pk);

    // -- ctx chain --
    k_gemm_m<true,  true ><<<dim3(16, 8), 256, 0, stream>>>(I0, I1, I2, wc1p, bc1, tmp, 3 * HH);
    k_gemm_m<false, false><<<dim3(16, 8), 256, 0, stream>>>(tmp, nullptr, nullptr, wc2p, bc2, ctx, HH);
    k_gemm_m<false, false><<<dim3(16, 8), 256, 0, stream>>>(ctx, nullptr, nullptr, wvp, bv, tmp, HH);
    k_gemm_m<false, false><<<dim3(16, 8), 256, 0, stream>>>(tmp, nullptr, nullptr, wop, bo, attn, HH);

    k_bc<<<dim3(192), 512, 0, stream>>>(ctx, MQ, wk1p, bk1, wk2p, bk2, wf1p, bf1, Wf2, bf2v,
                                        coarse, conf);
    k_ef<<<dim3(BB * KK), 512, 0, stream>>>(attn, coarse, Wt, bt, lng, lnb,
                                            wr1p, br1, Wr2, br2, pred);
    k_softmax<<<dim3(2), 256, 0, stream>>>(conf, probs);
}

// Round 8
// 324.846 us; speedup vs baseline: 1.1724x; 1.0181x over previous
//
#include <hip/hip_runtime.h>
#include <math.h>

#define BB 512
#define HH 512
#define KK 6
#define TT 60
#define OO 2
#define H2 1024
#define TO 120
#define RFP 520   // padded LDS row stride (bf16 elems), 1040B = 65x16B
#define HSP 1032  // padded h row stride (bf16 elems)

typedef __bf16 bf16x8 __attribute__((ext_vector_type(8)));
typedef float  f32x4  __attribute__((ext_vector_type(4)));
typedef float  f32x16 __attribute__((ext_vector_type(16)));

__device__ __forceinline__ float bf2f(unsigned short u) {
    union { unsigned int i; float f; } v; v.i = ((unsigned int)u) << 16; return v.f;
}
__device__ __forceinline__ unsigned short f2bf(float f) {
    union { float f; unsigned int i; } v; v.f = f;
    unsigned int b = v.i;
    return (unsigned short)((b + 0x7FFFu + ((b >> 16) & 1u)) >> 16); // RNE
}
// pair-pack via HW cvt (v_cvt_pk_bf16_f32, RNE on gfx950)
__device__ __forceinline__ unsigned int pack2bf(float a, float b) {
    union { __bf16 h[2]; unsigned int u; } v;
    v.h[0] = (__bf16)a; v.h[1] = (__bf16)b;
    return v.u;
}
__device__ __forceinline__ float gelu_exact(float x) {
    return 0.5f * x * (1.0f + erff(x * 0.70710678118654752f));
}

#if defined(__has_builtin)
#  if __has_builtin(__builtin_amdgcn_rcpf)
#    define FAST_RCP(x) __builtin_amdgcn_rcpf(x)
#  endif
#  if __has_builtin(__builtin_amdgcn_exp2f)
#    define FAST_EXP2(x) __builtin_amdgcn_exp2f(x)
#  endif
#endif
#ifndef FAST_RCP
#  define FAST_RCP(x) (1.0f / (x))
#endif
#ifndef FAST_EXP2
#  define FAST_EXP2(x) __expf((x) * 0.69314718056f)
#endif

// tanh-form GELU, constants pre-scaled by log2(e); ~7 VALU inst, err ~3e-4.
__device__ __forceinline__ float gelu_cheap(float x) {
    float x2 = x * x;
    float z = x * fmaf(0.10294324f, x2, 2.3022082f);
    float e = FAST_EXP2(-z);
    return x * FAST_RCP(1.0f + e);
}

struct F8 { float v[8]; };
__device__ __forceinline__ F8 load8f(const float* p) {
    F8 r;
    float4 a = *(const float4*)p;
    float4 b = *(const float4*)(p + 4);
    r.v[0] = a.x; r.v[1] = a.y; r.v[2] = a.z; r.v[3] = a.w;
    r.v[4] = b.x; r.v[5] = b.y; r.v[6] = b.z; r.v[7] = b.w;
    return r;
}
__device__ __forceinline__ F8 load8b(const unsigned short* p) {
    ushort4 a = *(const ushort4*)p;
    ushort4 b = *(const ushort4*)(p + 4);
    F8 r;
    r.v[0] = bf2f(a.x); r.v[1] = bf2f(a.y); r.v[2] = bf2f(a.z); r.v[3] = bf2f(a.w);
    r.v[4] = bf2f(b.x); r.v[5] = bf2f(b.y); r.v[6] = bf2f(b.z); r.v[7] = bf2f(b.w);
    return r;
}

// ---- fragment-order weight pack: B-records of 512 bf16 (1KB), one wave-load each ----
// NC=16 (16x16x32 MFMA): rec[ln*8+j] = W[step*32 + (ln>>4)*8 + j][nch*16 + (ln&15)]
// NC=32 (32x32x16 MFMA): rec[ln*8+j] = W[step*16 + (ln>>5)*8 + j][nch*32 + (ln&31)]
// -> consumer load: base + (nch*steps + step)*512 + ln*8  (coalesced 1KB/wave)
struct PKD { const float* src; unsigned short* dst; int F, N, NC, nch, steps, Z; };
struct PK8 { PKD e[8]; };

__global__ void k_pack(PK8 d) {
    int rid = blockIdx.x * 4 + (threadIdx.x >> 6);
    const int ln = threadIdx.x & 63;
    int i = 0;
    while (i < 7) {
        int tot = d.e[i].Z * d.e[i].nch * d.e[i].steps;
        if (rid < tot) break;
        rid -= tot; ++i;
    }
    const PKD e = d.e[i];
    const int per = e.nch * e.steps;
    const int z = rid / per;
    const int r = rid - z * per;
    const int nch = r / e.steps, step = r - nch * e.steps;
    const float* src = e.src + (size_t)z * e.F * e.N;
    unsigned short* dst = e.dst + ((size_t)z * per + r) * 512 + ln * 8;
    int f_base, n;
    if (e.NC == 16) { f_base = step * 32 + (ln >> 4) * 8; n = nch * 16 + (ln & 15); }
    else            { f_base = step * 16 + (ln >> 5) * 8; n = nch * 32 + (ln & 31); }
    if (n >= e.N) n = e.N - 1;   // clamp (Wk2: logical 128 cols over 120 real)
    unsigned int pk[4];
#pragma unroll
    for (int j = 0; j < 4; ++j) {
        unsigned short lo = f2bf(src[(size_t)(f_base + 2 * j) * e.N + n]);
        unsigned short hi = f2bf(src[(size_t)(f_base + 2 * j + 1) * e.N + n]);
        pk[j] = (unsigned int)lo | ((unsigned int)hi << 16);
    }
    *(uint4*)dst = make_uint4(pk[0], pk[1], pk[2], pk[3]);
}

// --------- MFMA ctx-chain GEMM, 32x32 tiles, grid 16x16 = 256 blocks (full GPU) ---------
template <bool CONCAT, bool GELU>
__launch_bounds__(256)
__global__ void k_gemm_m(const void* __restrict__ A0, const void* __restrict__ A1,
                         const void* __restrict__ A2, const unsigned short* __restrict__ BP,
                         const float* __restrict__ bias, unsigned short* __restrict__ C,
                         int Kd) {
    __shared__ __align__(16) unsigned short As[32 * RFP];
    const int tid = threadIdx.x;
    const int bm = blockIdx.x * 32;
    const int bn = blockIdx.y * 32;
    const int w = tid >> 6, ln = tid & 63;
    const int lane15 = ln & 15, quad = ln >> 4;
    const int mh = w >> 1;            // m-half: rows mh*16
    const int ng = w & 1;             // n-group: cols ng*16
    const int n = bn + ng * 16 + lane15;
    const int nchunks = Kd / HH;
    const int stepsTot = Kd / 32;
    const int nchB = blockIdx.y * 2 + ng;

    f32x4 acc0 = {0.f, 0.f, 0.f, 0.f};

    for (int kc = 0; kc < nchunks; ++kc) {
        {
            int r = tid >> 3, c0 = (tid & 7) * 64;
            unsigned short* dp = As + r * RFP + c0;
            if (CONCAT) {
                const float* src = (kc == 0) ? (const float*)A0
                                 : (kc == 1) ? (const float*)A1 : (const float*)A2;
                const float* sp = src + (bm + r) * HH + c0;
                for (int c = 0; c < 64; c += 8) {
                    F8 v = load8f(sp + c);
                    unsigned int pk[4];
#pragma unroll
                    for (int j = 0; j < 4; ++j)
                        pk[j] = pack2bf(v.v[2 * j], v.v[2 * j + 1]);
                    *(uint4*)(dp + c) = make_uint4(pk[0], pk[1], pk[2], pk[3]);
                }
            } else {
                const unsigned short* sp = (const unsigned short*)A0 + (bm + r) * HH + c0;
                for (int c = 0; c < 64; c += 8)
                    *(uint4*)(dp + c) = *(const uint4*)(sp + c);
            }
        }
        __syncthreads();
        const unsigned short* bp = BP + ((size_t)nchB * stepsTot + kc * 16) * 512 + ln * 8;
#pragma unroll
        for (int f0 = 0; f0 < HH; f0 += 32) {
            bf16x8 a0 = *(const bf16x8*)(As + (mh * 16 + lane15) * RFP + f0 + quad * 8);
            bf16x8 bf = *(const bf16x8*)(bp);
            bp += 512;
            acc0 = __builtin_amdgcn_mfma_f32_16x16x32_bf16(a0, bf, acc0, 0, 0, 0);
        }
        __syncthreads();
    }
    const float bb = bias[n];
#pragma unroll
    for (int reg = 0; reg < 4; ++reg) {
        float v0 = acc0[reg] + bb;
        if (GELU) v0 = gelu_exact(v0);
        C[(bm + mh * 16 + quad * 4 + reg) * HH + n] = f2bf(v0);
    }
}

// ---------------- k_bcg: fused k_bc (blocks 0..191) + v-GEMM (blocks 192..319) ----------------
// Both depend only on ctx; merging co-schedules them (k_bc alone leaves 64+ CUs idle).
__launch_bounds__(512)
__global__ void k_bcg(const unsigned short* __restrict__ ctx, const float* __restrict__ mq,
                      const unsigned short* __restrict__ Wk1P, const float* __restrict__ bk1,
                      const unsigned short* __restrict__ Wk2P, const float* __restrict__ bk2,
                      const unsigned short* __restrict__ Wf1P, const float* __restrict__ bf1,
                      const float* __restrict__ Wf2, const float* __restrict__ bf2v,
                      unsigned short* __restrict__ coarse_out, float* __restrict__ conf_out,
                      const unsigned short* __restrict__ WvP, const float* __restrict__ bv,
                      unsigned short* __restrict__ vout)
{
    __shared__ __align__(16) unsigned short shbuf[24832];   // 49,664 B union

    const int tid = threadIdx.x;
    const int w = tid >> 6;
    const int ln = tid & 63;
    const int lane15 = ln & 15;
    const int quad = ln >> 4;

    if (blockIdx.x >= 192) {
        // ===== v = ctx @ Wv + bv  (32x64 tile, 8 waves, Kd=512) =====
        unsigned short* As = shbuf;                          // 32*RFP shorts = 33,280 B
        const int gbid = blockIdx.x - 192;                   // 0..127
        const int bm = (gbid & 15) * 32;
        const int gy = gbid >> 4;                            // 0..7
        const int bn = gy * 64;
        const int mh = w >> 2;                               // 0..1
        const int ng = w & 3;                                // 0..3
        const int n = bn + ng * 16 + lane15;
        const int nchB = gy * 4 + ng;

        // stage A tile: 32 rows x 512 cols bf16 (512 threads)
        {
            int r = tid >> 4, c0 = (tid & 15) * 32;
            const unsigned short* sp = ctx + (bm + r) * HH + c0;
            unsigned short* dp = As + r * RFP + c0;
            for (int c = 0; c < 32; c += 8)
                *(uint4*)(dp + c) = *(const uint4*)(sp + c);
        }
        __syncthreads();
        f32x4 acc0 = {0.f, 0.f, 0.f, 0.f};
        const unsigned short* bp = WvP + (size_t)nchB * 16 * 512 + ln * 8;
#pragma unroll
        for (int f0 = 0; f0 < HH; f0 += 32) {
            bf16x8 a0 = *(const bf16x8*)(As + (mh * 16 + lane15) * RFP + f0 + quad * 8);
            bf16x8 bf = *(const bf16x8*)(bp);
            bp += 512;
            acc0 = __builtin_amdgcn_mfma_f32_16x16x32_bf16(a0, bf, acc0, 0, 0, 0);
        }
        const float bb = bv[n];
#pragma unroll
        for (int reg = 0; reg < 4; ++reg)
            vout[(bm + mh * 16 + quad * 4 + reg) * HH + n] = f2bf(acc0[reg] + bb);
        return;
    }

    // ===== k_bc body =====
    unsigned short* mf = shbuf;                  // 16*RFP = 16,640 B
    unsigned short* hs = shbuf + 16 * RFP;       // 16*HSP = 33,024 B
    const int k = blockIdx.x % KK;
    const int b0 = (blockIdx.x / KK) * 16;

    // ---- stage mf = bf16(ctx + mq[k]) rows b0..b0+15 ----
    {
        int r = tid >> 5;               // 0..15
        int c0 = (tid & 31) * 16;
        const unsigned short* cp = ctx + (b0 + r) * HH + c0;
        const float* qp = mq + k * HH + c0;
        unsigned short* dp = mf + r * RFP + c0;
        for (int c = 0; c < 16; c += 8) {
            F8 cv = load8b(cp + c);
            F8 qv = load8f(qp + c);
            unsigned int pk[4];
#pragma unroll
            for (int j = 0; j < 4; ++j)
                pk[j] = pack2bf(cv.v[2 * j] + qv.v[2 * j], cv.v[2 * j + 1] + qv.v[2 * j + 1]);
            *(uint4*)(dp + c) = make_uint4(pk[0], pk[1], pk[2], pk[3]);
        }
    }
    __syncthreads();

    // ---- GEMM1: h = gelu(mf @ Wk1[k] + bk1[k]) -> hs. Packed-B: nch = w*8+g, 16 steps ----
    {
        const unsigned short* wk1p = Wk1P + (size_t)k * (64 * 16 * 512);
        const float* bk1p = bk1 + k * H2;
        for (int g = 0; g < 8; ++g) {
            const int n = w * 128 + g * 16 + lane15;
            f32x4 acc0 = {0.f,0.f,0.f,0.f};
            const unsigned short* bp = wk1p + (size_t)((w * 8 + g) * 16) * 512 + ln * 8;
#pragma unroll
            for (int f0 = 0; f0 < HH; f0 += 32) {
                bf16x8 a0 = *(const bf16x8*)(mf + lane15 * RFP + f0 + quad * 8);
                bf16x8 bf = *(const bf16x8*)(bp);
                bp += 512;
                acc0 = __builtin_amdgcn_mfma_f32_16x16x32_bf16(a0, bf, acc0, 0, 0, 0);
            }
            const float bias = bk1p[n];
#pragma unroll
            for (int reg = 0; reg < 4; ++reg)
                hs[(quad * 4 + reg) * HSP + n] = f2bf(gelu_exact(acc0[reg] + bias));
        }
    }
    __syncthreads();

    // ---- GEMM2: coarse = h @ Wk2[k] + bk2[k]. Packed-B: nch = w, 32 steps (clamp baked) ----
    {
        const unsigned short* wk2p = Wk2P + (size_t)k * (8 * 32 * 512);
        const int n = w * 16 + lane15;
        f32x4 acc0 = {0.f,0.f,0.f,0.f};
        const unsigned short* bp = wk2p + (size_t)(w * 32) * 512 + ln * 8;
#pragma unroll
        for (int f0 = 0; f0 < H2; f0 += 32) {
            bf16x8 a0 = *(const bf16x8*)(hs + lane15 * HSP + f0 + quad * 8);
            bf16x8 bf = *(const bf16x8*)(bp);
            bp += 512;
            acc0 = __builtin_amdgcn_mfma_f32_16x16x32_bf16(a0, bf, acc0, 0, 0, 0);
        }
        if (n < TO) {
            const float bias = bk2[k * TO + n];
#pragma unroll
            for (int reg = 0; reg < 4; ++reg)
                coarse_out[((b0 + quad * 4 + reg) * KK + k) * TO + n] = f2bf(acc0[reg] + bias);
        }
    }

    // ---- GEMM3 (wave 0): conf = relu(mf @ Wf1 + bf1) @ Wf2 + bf2. Packed-B: nch = nt ----
    if (w == 0) {
        f32x4 acc[4];
#pragma unroll
        for (int nt = 0; nt < 4; ++nt) { f32x4 z = {0.f,0.f,0.f,0.f}; acc[nt] = z; }
#pragma unroll
        for (int f0 = 0; f0 < HH; f0 += 32) {
            const int step = f0 >> 5;
            bf16x8 a0 = *(const bf16x8*)(mf + lane15 * RFP + f0 + quad * 8);
#pragma unroll
            for (int nt = 0; nt < 4; ++nt) {
                bf16x8 bf = *(const bf16x8*)(Wf1P + (size_t)(nt * 16 + step) * 512 + ln * 8);
                acc[nt] = __builtin_amdgcn_mfma_f32_16x16x32_bf16(a0, bf, acc[nt], 0, 0, 0);
            }
        }
        const float b2 = bf2v[0];
#pragma unroll
        for (int reg = 0; reg < 4; ++reg) {
            float s = 0.f;
#pragma unroll
            for (int nt = 0; nt < 4; ++nt) {
                const int n = nt * 16 + lane15;
                s = fmaf(fmaxf(acc[nt][reg] + bf1[n], 0.f), Wf2[n], s);
            }
#pragma unroll
            for (int off = 1; off < 16; off <<= 1) s += __shfl_xor(s, off);
            if (lane15 == 0)
                conf_out[(b0 + quad * 4 + reg) * KK + k] = s + b2;
        }
    }
}

// ---------------- k_ef: per (b,k) block, 8 waves, packed-B, 2 blocks/CU; k==0 blocks also
//                  compute mode_probs softmax for their b (one lane, hidden under Phase E) ----------------
__launch_bounds__(512, 4)
__global__ void k_ef(
    const unsigned short* __restrict__ attn, const unsigned short* __restrict__ coarse_ws,
    const float* __restrict__ Wt,  const float* __restrict__ bt,
    const float* __restrict__ lng, const float* __restrict__ lnb,
    const unsigned short* __restrict__ Wr1P, const float* __restrict__ br1,
    const float* __restrict__ Wr2, const float* __restrict__ br2,
    float* __restrict__ pred_out,
    const float* __restrict__ conf, float* __restrict__ probs)
{
    __shared__ __align__(16) unsigned short rf[64 * RFP];  // 66,560 B
    __shared__ float coarse[TO];                           // 480 B
    __shared__ float br1s[HH];                             // 2,048 B
    __shared__ float2 wr2s[HH];                            // 4,096 B
    __shared__ float po2[8][64][2];                        // 4,096 B
    // total 77,280 B -> 2 blocks/CU

    const int tid = threadIdx.x;
    const int b = blockIdx.x / KK;
    const int k = blockIdx.x % KK;
    const int w = tid >> 6;          // 0..7
    const int ln = tid & 63;
    const int lane31 = ln & 31;
    const int hf = ln >> 5;
    const int cbase = ln * 8;

    const unsigned short* attb = attn + b * HH;

    if (tid < TO) coarse[tid] = bf2f(coarse_ws[(b * KK + k) * TO + tid]);
    br1s[tid] = br1[k * HH + tid];
    wr2s[tid] = ((const float2*)Wr2)[(size_t)k * HH + tid];

    // fold mode_probs softmax into k==0 blocks (conf ready: k_bcg completed)
    if (k == 0 && tid == 448) {
        float v[KK]; float m = -1e30f;
#pragma unroll
        for (int i = 0; i < KK; ++i) { v[i] = conf[b * KK + i]; m = fmaxf(m, v[i]); }
        float s = 0.f;
#pragma unroll
        for (int i = 0; i < KK; ++i) { v[i] = __expf(v[i] - m); s += v[i]; }
        float inv = 1.0f / s;
#pragma unroll
        for (int i = 0; i < KK; ++i) probs[b * KK + i] = v[i] * inv;
    }
    __syncthreads();

    // ---- Phase E: traj=gelu(coarse@Wt+bt); rf = LN(traj+attn)*g+b (bf16) ----
    {
        F8 w0 = load8f(Wt + cbase);
        F8 w1 = load8f(Wt + HH + cbase);
        F8 b8 = load8f(bt + cbase);
        F8 g8 = load8f(lng + cbase);
        F8 bb8 = load8f(lnb + cbase);
        F8 a8 = load8b(attb + cbase);
#pragma unroll
        for (int r = 0; r < 8; ++r) {
            int t = w + 8 * r;
            if (t < 60) {
                float co0 = coarse[2 * t], co1 = coarse[2 * t + 1];
                float x[8]; float s = 0.f, s2 = 0.f;
#pragma unroll
                for (int j = 0; j < 8; ++j) {
                    float vv = fmaf(co0, w0.v[j], fmaf(co1, w1.v[j], b8.v[j]));
                    vv = gelu_cheap(vv) + a8.v[j];
                    x[j] = vv; s += vv; s2 = fmaf(vv, vv, s2);
                }
#pragma unroll
                for (int off = 32; off > 0; off >>= 1) {
                    s += __shfl_xor(s, off);
                    s2 += __shfl_xor(s2, off);
                }
                float mean = s * (1.0f / HH);
                float var = fmaf(-mean, mean, s2 * (1.0f / HH));
                float inv = rsqrtf(var + 1e-5f);
                unsigned int pk[4];
#pragma unroll
                for (int j = 0; j < 4; ++j) {
                    float y0 = fmaf((x[2 * j] - mean) * inv, g8.v[2 * j], bb8.v[2 * j]);
                    float y1 = fmaf((x[2 * j + 1] - mean) * inv, g8.v[2 * j + 1], bb8.v[2 * j + 1]);
                    pk[j] = pack2bf(y0, y1);
                }
                *(uint4*)(rf + t * RFP + cbase) = make_uint4(pk[0], pk[1], pk[2], pk[3]);
            } else {
                *(uint4*)(rf + t * RFP + cbase) = make_uint4(0, 0, 0, 0);
            }
        }
    }
    __syncthreads();

    // ---- Phase F: r=gelu(rf@Wr1+br1); offsets=r@Wr2 (32x32x16 MFMA, swapped operands,
    //      packed-B records [nch=16][step=32][512]; wave w owns nch 2w, 2w+1) ----
    {
        const unsigned short* bp0 = Wr1P + (size_t)k * (16 * 32 * 512)
                                  + (size_t)(w * 2) * 32 * 512 + ln * 8;
        const unsigned short* bp1 = bp0 + 32 * 512;   // next nch
        const int n0 = w * 64;
        const unsigned short* a0p = rf + lane31 * RFP + hf * 8;
        const unsigned short* a1p = a0p + 32 * RFP;

        f32x16 acc00 = {0.f,0.f,0.f,0.f,0.f,0.f,0.f,0.f,0.f,0.f,0.f,0.f,0.f,0.f,0.f,0.f};
        f32x16 acc01 = acc00, acc10 = acc00, acc11 = acc00;

        __builtin_amdgcn_s_setprio(1);
#pragma unroll
        for (int st = 0; st < 32; ++st) {
            const int k0 = st * 16;
            bf16x8 A0 = *(const bf16x8*)(a0p + k0);
            bf16x8 A1 = *(const bf16x8*)(a1p + k0);
            bf16x8 B0 = *(const bf16x8*)(bp0 + st * 512);
            bf16x8 B1 = *(const bf16x8*)(bp1 + st * 512);
            acc00 = __builtin_amdgcn_mfma_f32_32x32x16_bf16(B0, A0, acc00, 0, 0, 0);
            acc01 = __builtin_amdgcn_mfma_f32_32x32x16_bf16(B1, A0, acc01, 0, 0, 0);
            acc10 = __builtin_amdgcn_mfma_f32_32x32x16_bf16(B0, A1, acc10, 0, 0, 0);
            acc11 = __builtin_amdgcn_mfma_f32_32x32x16_bf16(B1, A1, acc11, 0, 0, 0);
        }
        __builtin_amdgcn_s_setprio(0);

        // In-lane contraction over n (regs); lane = m (time-step).
        float p00 = 0.f, p01 = 0.f, p10 = 0.f, p11 = 0.f;  // [m-half][o]
#pragma unroll
        for (int nt = 0; nt < 2; ++nt) {
#pragma unroll
            for (int reg = 0; reg < 16; ++reg) {
                const int n = n0 + nt * 32 + (reg & 3) + 8 * (reg >> 2) + 4 * hf;
                const float bb = br1s[n];
                const float2 w2 = wr2s[n];
                const float a0v = nt ? acc01[reg] : acc00[reg];
                const float a1v = nt ? acc11[reg] : acc10[reg];
                const float rv0 = gelu_cheap(a0v + bb);
                const float rv1 = gelu_cheap(a1v + bb);
                p00 = fmaf(rv0, w2.x, p00);
                p01 = fmaf(rv0, w2.y, p01);
                p10 = fmaf(rv1, w2.x, p10);
                p11 = fmaf(rv1, w2.y, p11);
            }
        }
        p00 += __shfl_xor(p00, 32);
        p01 += __shfl_xor(p01, 32);
        p10 += __shfl_xor(p10, 32);
        p11 += __shfl_xor(p11, 32);
        if (ln < 32) {
            *(float2*)&po2[w][lane31][0]      = make_float2(p00, p01);
            *(float2*)&po2[w][32 + lane31][0] = make_float2(p10, p11);
        }
    }
    __syncthreads();

    if (tid < TO) {
        int t = tid >> 1, o = tid & 1;
        float s = 0.f;
#pragma unroll
        for (int ww = 0; ww < 8; ++ww) s += po2[ww][t][o];
        pred_out[((b * KK + k) * TT + t) * 2 + o] = coarse[tid] + s + br2[k * 2 + o];
    }
}

extern "C" void kernel_launch(void* const* d_in, const int* in_sizes, int n_in,
                              void* d_out, int out_size, void* d_ws, size_t ws_size,
                              hipStream_t stream) {
    const float* I0  = (const float*)d_in[0];
    const float* I1  = (const float*)d_in[1];
    const float* I2  = (const float*)d_in[2];
    const float* MQ  = (const float*)d_in[3];
    const float* Wc1 = (const float*)d_in[4];
    const float* bc1 = (const float*)d_in[5];
    const float* Wc2 = (const float*)d_in[6];
    const float* bc2 = (const float*)d_in[7];
    const float* Wk1 = (const float*)d_in[8];
    const float* bk1 = (const float*)d_in[9];
    const float* Wk2 = (const float*)d_in[10];
    const float* bk2 = (const float*)d_in[11];
    const float* Wt  = (const float*)d_in[12];
    const float* bt  = (const float*)d_in[13];
    const float* Wv  = (const float*)d_in[18];
    const float* bv  = (const float*)d_in[19];
    const float* Wo  = (const float*)d_in[20];
    const float* bo  = (const float*)d_in[21];
    const float* lng = (const float*)d_in[22];
    const float* lnb = (const float*)d_in[23];
    const float* Wr1 = (const float*)d_in[24];
    const float* br1 = (const float*)d_in[25];
    const float* Wr2 = (const float*)d_in[26];
    const float* br2 = (const float*)d_in[27];
    const float* Wf1 = (const float*)d_in[28];
    const float* bf1 = (const float*)d_in[29];
    const float* Wf2 = (const float*)d_in[30];
    const float* bf2v = (const float*)d_in[31];

    // workspace layout (bf16 elems)
    unsigned short* wsu   = (unsigned short*)d_ws;
    unsigned short* wc1p  = wsu;                 //   786,432  (32nch x 48st x 512)
    unsigned short* wc2p  = wsu + 786432;        //   262,144
    unsigned short* wvp   = wsu + 1048576;       //   262,144
    unsigned short* wop   = wsu + 1310720;       //   262,144
    unsigned short* wk1p  = wsu + 1572864;       // 3,145,728  (K x 64nch x 16st x 512)
    unsigned short* wk2p  = wsu + 4718592;       //   786,432  (K x 8nch x 32st x 512, clamped)
    unsigned short* wf1p  = wsu + 5505024;       //    32,768  (4nch x 16st x 512)
    unsigned short* wr1p  = wsu + 5537792;       // 1,572,864  (K x 16nch x 32st x 512)
    unsigned short* ctx   = wsu + 7110656;       //   262,144
    unsigned short* attn  = wsu + 7372800;       //   262,144
    unsigned short* tmp   = wsu + 7634944;       //   262,144
    unsigned short* coarse= wsu + 7897088;       //   368,640
    float* conf = (float*)(wsu + 8265728);       //     3,072 fp32

    float* pred = (float*)d_out;
    float* probs = pred + BB * KK * TT * OO;

    // -- prep: all GEMM B-weights -> bf16 fragment-order records, one launch --
    PK8 pk;
    pk.e[0] = {Wc1, wc1p, 3 * HH, HH, 16, 32, 48, 1};   // 1536 recs
    pk.e[1] = {Wc2, wc2p, HH, HH, 16, 32, 16, 1};       //  512
    pk.e[2] = {Wv,  wvp,  HH, HH, 16, 32, 16, 1};       //  512
    pk.e[3] = {Wo,  wop,  HH, HH, 16, 32, 16, 1};       //  512
    pk.e[4] = {Wk1, wk1p, HH, H2, 16, 64, 16, KK};      // 6144
    pk.e[5] = {Wk2, wk2p, H2, TO, 16, 8, 32, KK};       // 1536 (clamped cols)
    pk.e[6] = {Wf1, wf1p, HH, 64, 16, 4, 16, 1};        //   64
    pk.e[7] = {Wr1, wr1p, HH, HH, 32, 16, 32, KK};      // 3072
    k_pack<<<dim3(3472), 256, 0, stream>>>(pk);

    // -- ctx chain (g1, g2 at full-GPU grid 16x16) --
    k_gemm_m<true,  true ><<<dim3(16, 16), 256, 0, stream>>>(I0, I1, I2, wc1p, bc1, tmp, 3 * HH);
    k_gemm_m<false, false><<<dim3(16, 16), 256, 0, stream>>>(tmp, nullptr, nullptr, wc2p, bc2, ctx, HH);

    // -- fused: k_bc (blocks 0..191) + v = ctx@Wv+bv (blocks 192..319) --
    k_bcg<<<dim3(320), 512, 0, stream>>>(ctx, MQ, wk1p, bk1, wk2p, bk2, wf1p, bf1, Wf2, bf2v,
                                         coarse, conf, wvp, bv, tmp);

    // -- attn = v @ Wo + bo --
    k_gemm_m<false, false><<<dim3(16, 16), 256, 0, stream>>>(tmp, nullptr, nullptr, wop, bo, attn, HH);

    // -- refine + predictions (+ folded softmax in k==0 blocks) --
    k_ef<<<dim3(BB * KK), 512, 0, stream>>>(attn, coarse, Wt, bt, lng, lnb,
                                            wr1p, br1, Wr2, br2, pred, conf, probs);
}

// Round 9
// 313.821 us; speedup vs baseline: 1.2136x; 1.0351x over previous
//
#include <hip/hip_runtime.h>
#include <math.h>

#define BB 512
#define HH 512
#define KK 6
#define TT 60
#define OO 2
#define H2 1024
#define TO 120
#define RFP 520   // padded LDS row stride (bf16 elems), 1040B = 65x16B
#define HSP 1032  // padded h row stride (bf16 elems)

typedef __bf16 bf16x8 __attribute__((ext_vector_type(8)));
typedef float  f32x4  __attribute__((ext_vector_type(4)));
typedef float  f32x16 __attribute__((ext_vector_type(16)));

__device__ __forceinline__ float bf2f(unsigned short u) {
    union { unsigned int i; float f; } v; v.i = ((unsigned int)u) << 16; return v.f;
}
__device__ __forceinline__ unsigned short f2bf(float f) {
    union { float f; unsigned int i; } v; v.f = f;
    unsigned int b = v.i;
    return (unsigned short)((b + 0x7FFFu + ((b >> 16) & 1u)) >> 16); // RNE
}
// pair-pack via HW cvt (v_cvt_pk_bf16_f32, RNE on gfx950)
__device__ __forceinline__ unsigned int pack2bf(float a, float b) {
    union { __bf16 h[2]; unsigned int u; } v;
    v.h[0] = (__bf16)a; v.h[1] = (__bf16)b;
    return v.u;
}
__device__ __forceinline__ float gelu_exact(float x) {
    return 0.5f * x * (1.0f + erff(x * 0.70710678118654752f));
}

#if defined(__has_builtin)
#  if __has_builtin(__builtin_amdgcn_rcpf)
#    define FAST_RCP(x) __builtin_amdgcn_rcpf(x)
#  endif
#  if __has_builtin(__builtin_amdgcn_exp2f)
#    define FAST_EXP2(x) __builtin_amdgcn_exp2f(x)
#  endif
#endif
#ifndef FAST_RCP
#  define FAST_RCP(x) (1.0f / (x))
#endif
#ifndef FAST_EXP2
#  define FAST_EXP2(x) __expf((x) * 0.69314718056f)
#endif

// tanh-form GELU, constants pre-scaled by log2(e); ~7 VALU inst, err ~3e-4.
__device__ __forceinline__ float gelu_cheap(float x) {
    float x2 = x * x;
    float z = x * fmaf(0.10294324f, x2, 2.3022082f);
    float e = FAST_EXP2(-z);
    return x * FAST_RCP(1.0f + e);
}

struct F8 { float v[8]; };
__device__ __forceinline__ F8 load8f(const float* p) {
    F8 r;
    float4 a = *(const float4*)p;
    float4 b = *(const float4*)(p + 4);
    r.v[0] = a.x; r.v[1] = a.y; r.v[2] = a.z; r.v[3] = a.w;
    r.v[4] = b.x; r.v[5] = b.y; r.v[6] = b.z; r.v[7] = b.w;
    return r;
}
__device__ __forceinline__ F8 load8b(const unsigned short* p) {
    ushort4 a = *(const ushort4*)p;
    ushort4 b = *(const ushort4*)(p + 4);
    F8 r;
    r.v[0] = bf2f(a.x); r.v[1] = bf2f(a.y); r.v[2] = bf2f(a.z); r.v[3] = bf2f(a.w);
    r.v[4] = bf2f(b.x); r.v[5] = bf2f(b.y); r.v[6] = bf2f(b.z); r.v[7] = bf2f(b.w);
    return r;
}

// ---- fragment-order weight pack: B-records of 512 bf16 (1KB), one wave-load each ----
// NC=16 (16x16x32 MFMA): rec[ln*8+j] = W[step*32 + (ln>>4)*8 + j][nch*16 + (ln&15)]
// NC=32 (32x32x16 MFMA): rec[ln*8+j] = W[step*16 + (ln>>5)*8 + j][nch*32 + (ln&31)]
// -> consumer load: base + (nch*steps + step)*512 + ln*8  (coalesced 1KB/wave)
struct PKD { const float* src; unsigned short* dst; int F, N, NC, nch, steps, Z; };
struct PK8 { PKD e[8]; };

__global__ void k_pack(PK8 d) {
    int rid = blockIdx.x * 4 + (threadIdx.x >> 6);
    const int ln = threadIdx.x & 63;
    int i = 0;
    while (i < 7) {
        int tot = d.e[i].Z * d.e[i].nch * d.e[i].steps;
        if (rid < tot) break;
        rid -= tot; ++i;
    }
    const PKD e = d.e[i];
    const int per = e.nch * e.steps;
    const int z = rid / per;
    const int r = rid - z * per;
    const int nch = r / e.steps, step = r - nch * e.steps;
    const float* src = e.src + (size_t)z * e.F * e.N;
    unsigned short* dst = e.dst + ((size_t)z * per + r) * 512 + ln * 8;
    int f_base, n;
    if (e.NC == 16) { f_base = step * 32 + (ln >> 4) * 8; n = nch * 16 + (ln & 15); }
    else            { f_base = step * 16 + (ln >> 5) * 8; n = nch * 32 + (ln & 31); }
    if (n >= e.N) n = e.N - 1;   // clamp (Wk2: logical 128 cols over 120 real)
    unsigned int pk[4];
#pragma unroll
    for (int j = 0; j < 4; ++j) {
        unsigned short lo = f2bf(src[(size_t)(f_base + 2 * j) * e.N + n]);
        unsigned short hi = f2bf(src[(size_t)(f_base + 2 * j + 1) * e.N + n]);
        pk[j] = (unsigned int)lo | ((unsigned int)hi << 16);
    }
    *(uint4*)dst = make_uint4(pk[0], pk[1], pk[2], pk[3]);
}

// --------- MFMA ctx-chain GEMM, 32x32 tiles, grid 16x16 = 256 blocks (full GPU) ---------
template <bool CONCAT, bool GELU>
__launch_bounds__(256)
__global__ void k_gemm_m(const void* __restrict__ A0, const void* __restrict__ A1,
                         const void* __restrict__ A2, const unsigned short* __restrict__ BP,
                         const float* __restrict__ bias, unsigned short* __restrict__ C,
                         int Kd) {
    __shared__ __align__(16) unsigned short As[32 * RFP];
    const int tid = threadIdx.x;
    const int bm = blockIdx.x * 32;
    const int bn = blockIdx.y * 32;
    const int w = tid >> 6, ln = tid & 63;
    const int lane15 = ln & 15, quad = ln >> 4;
    const int mh = w >> 1;            // m-half: rows mh*16
    const int ng = w & 1;             // n-group: cols ng*16
    const int n = bn + ng * 16 + lane15;
    const int nchunks = Kd / HH;
    const int stepsTot = Kd / 32;
    const int nchB = blockIdx.y * 2 + ng;

    f32x4 acc0 = {0.f, 0.f, 0.f, 0.f};

    for (int kc = 0; kc < nchunks; ++kc) {
        {
            int r = tid >> 3, c0 = (tid & 7) * 64;
            unsigned short* dp = As + r * RFP + c0;
            if (CONCAT) {
                const float* src = (kc == 0) ? (const float*)A0
                                 : (kc == 1) ? (const float*)A1 : (const float*)A2;
                const float* sp = src + (bm + r) * HH + c0;
                for (int c = 0; c < 64; c += 8) {
                    F8 v = load8f(sp + c);
                    unsigned int pk[4];
#pragma unroll
                    for (int j = 0; j < 4; ++j)
                        pk[j] = pack2bf(v.v[2 * j], v.v[2 * j + 1]);
                    *(uint4*)(dp + c) = make_uint4(pk[0], pk[1], pk[2], pk[3]);
                }
            } else {
                const unsigned short* sp = (const unsigned short*)A0 + (bm + r) * HH + c0;
                for (int c = 0; c < 64; c += 8)
                    *(uint4*)(dp + c) = *(const uint4*)(sp + c);
            }
        }
        __syncthreads();
        const unsigned short* bp = BP + ((size_t)nchB * stepsTot + kc * 16) * 512 + ln * 8;
#pragma unroll
        for (int f0 = 0; f0 < HH; f0 += 32) {
            bf16x8 a0 = *(const bf16x8*)(As + (mh * 16 + lane15) * RFP + f0 + quad * 8);
            bf16x8 bf = *(const bf16x8*)(bp);
            bp += 512;
            acc0 = __builtin_amdgcn_mfma_f32_16x16x32_bf16(a0, bf, acc0, 0, 0, 0);
        }
        __syncthreads();
    }
    const float bb = bias[n];
#pragma unroll
    for (int reg = 0; reg < 4; ++reg) {
        float v0 = acc0[reg] + bb;
        if (GELU) v0 = gelu_exact(v0);
        C[(bm + mh * 16 + quad * 4 + reg) * HH + n] = f2bf(v0);
    }
}

// ---------------- k_bcg: fused k_bc (blocks 0..191) + v-GEMM (blocks 192..319) ----------------
// Both depend only on ctx; merging co-schedules them (k_bc alone leaves 64+ CUs idle).
__launch_bounds__(512)
__global__ void k_bcg(const unsigned short* __restrict__ ctx, const float* __restrict__ mq,
                      const unsigned short* __restrict__ Wk1P, const float* __restrict__ bk1,
                      const unsigned short* __restrict__ Wk2P, const float* __restrict__ bk2,
                      const unsigned short* __restrict__ Wf1P, const float* __restrict__ bf1,
                      const float* __restrict__ Wf2, const float* __restrict__ bf2v,
                      unsigned short* __restrict__ coarse_out, float* __restrict__ conf_out,
                      const unsigned short* __restrict__ WvP, const float* __restrict__ bv,
                      unsigned short* __restrict__ vout)
{
    __shared__ __align__(16) unsigned short shbuf[24832];   // 49,664 B union

    const int tid = threadIdx.x;
    const int w = tid >> 6;
    const int ln = tid & 63;
    const int lane15 = ln & 15;
    const int quad = ln >> 4;

    if (blockIdx.x >= 192) {
        // ===== v = ctx @ Wv + bv  (32x64 tile, 8 waves, Kd=512) =====
        unsigned short* As = shbuf;                          // 32*RFP shorts = 33,280 B
        const int gbid = blockIdx.x - 192;                   // 0..127
        const int bm = (gbid & 15) * 32;
        const int gy = gbid >> 4;                            // 0..7
        const int bn = gy * 64;
        const int mh = w >> 2;                               // 0..1
        const int ng = w & 3;                                // 0..3
        const int n = bn + ng * 16 + lane15;
        const int nchB = gy * 4 + ng;

        // stage A tile: 32 rows x 512 cols bf16 (512 threads)
        {
            int r = tid >> 4, c0 = (tid & 15) * 32;
            const unsigned short* sp = ctx + (bm + r) * HH + c0;
            unsigned short* dp = As + r * RFP + c0;
            for (int c = 0; c < 32; c += 8)
                *(uint4*)(dp + c) = *(const uint4*)(sp + c);
        }
        __syncthreads();
        f32x4 acc0 = {0.f, 0.f, 0.f, 0.f};
        const unsigned short* bp = WvP + (size_t)nchB * 16 * 512 + ln * 8;
#pragma unroll
        for (int f0 = 0; f0 < HH; f0 += 32) {
            bf16x8 a0 = *(const bf16x8*)(As + (mh * 16 + lane15) * RFP + f0 + quad * 8);
            bf16x8 bf = *(const bf16x8*)(bp);
            bp += 512;
            acc0 = __builtin_amdgcn_mfma_f32_16x16x32_bf16(a0, bf, acc0, 0, 0, 0);
        }
        const float bb = bv[n];
#pragma unroll
        for (int reg = 0; reg < 4; ++reg)
            vout[(bm + mh * 16 + quad * 4 + reg) * HH + n] = f2bf(acc0[reg] + bb);
        return;
    }

    // ===== k_bc body =====
    unsigned short* mf = shbuf;                  // 16*RFP = 16,640 B
    unsigned short* hs = shbuf + 16 * RFP;       // 16*HSP = 33,024 B
    const int k = blockIdx.x % KK;
    const int b0 = (blockIdx.x / KK) * 16;

    // ---- stage mf = bf16(ctx + mq[k]) rows b0..b0+15 ----
    {
        int r = tid >> 5;               // 0..15
        int c0 = (tid & 31) * 16;
        const unsigned short* cp = ctx + (b0 + r) * HH + c0;
        const float* qp = mq + k * HH + c0;
        unsigned short* dp = mf + r * RFP + c0;
        for (int c = 0; c < 16; c += 8) {
            F8 cv = load8b(cp + c);
            F8 qv = load8f(qp + c);
            unsigned int pk[4];
#pragma unroll
            for (int j = 0; j < 4; ++j)
                pk[j] = pack2bf(cv.v[2 * j] + qv.v[2 * j], cv.v[2 * j + 1] + qv.v[2 * j + 1]);
            *(uint4*)(dp + c) = make_uint4(pk[0], pk[1], pk[2], pk[3]);
        }
    }
    __syncthreads();

    // ---- GEMM1: h = gelu(mf @ Wk1[k] + bk1[k]) -> hs. Packed-B: nch = w*8+g, 16 steps ----
    {
        const unsigned short* wk1p = Wk1P + (size_t)k * (64 * 16 * 512);
        const float* bk1p = bk1 + k * H2;
        for (int g = 0; g < 8; ++g) {
            const int n = w * 128 + g * 16 + lane15;
            f32x4 acc0 = {0.f,0.f,0.f,0.f};
            const unsigned short* bp = wk1p + (size_t)((w * 8 + g) * 16) * 512 + ln * 8;
#pragma unroll
            for (int f0 = 0; f0 < HH; f0 += 32) {
                bf16x8 a0 = *(const bf16x8*)(mf + lane15 * RFP + f0 + quad * 8);
                bf16x8 bf = *(const bf16x8*)(bp);
                bp += 512;
                acc0 = __builtin_amdgcn_mfma_f32_16x16x32_bf16(a0, bf, acc0, 0, 0, 0);
            }
            const float bias = bk1p[n];
#pragma unroll
            for (int reg = 0; reg < 4; ++reg)
                hs[(quad * 4 + reg) * HSP + n] = f2bf(gelu_exact(acc0[reg] + bias));
        }
    }
    __syncthreads();

    // ---- GEMM2: coarse = h @ Wk2[k] + bk2[k]. Packed-B: nch = w, 32 steps (clamp baked) ----
    {
        const unsigned short* wk2p = Wk2P + (size_t)k * (8 * 32 * 512);
        const int n = w * 16 + lane15;
        f32x4 acc0 = {0.f,0.f,0.f,0.f};
        const unsigned short* bp = wk2p + (size_t)(w * 32) * 512 + ln * 8;
#pragma unroll
        for (int f0 = 0; f0 < H2; f0 += 32) {
            bf16x8 a0 = *(const bf16x8*)(hs + lane15 * HSP + f0 + quad * 8);
            bf16x8 bf = *(const bf16x8*)(bp);
            bp += 512;
            acc0 = __builtin_amdgcn_mfma_f32_16x16x32_bf16(a0, bf, acc0, 0, 0, 0);
        }
        if (n < TO) {
            const float bias = bk2[k * TO + n];
#pragma unroll
            for (int reg = 0; reg < 4; ++reg)
                coarse_out[((b0 + quad * 4 + reg) * KK + k) * TO + n] = f2bf(acc0[reg] + bias);
        }
    }

    // ---- GEMM3 (wave 0): conf = relu(mf @ Wf1 + bf1) @ Wf2 + bf2. Packed-B: nch = nt ----
    if (w == 0) {
        f32x4 acc[4];
#pragma unroll
        for (int nt = 0; nt < 4; ++nt) { f32x4 z = {0.f,0.f,0.f,0.f}; acc[nt] = z; }
#pragma unroll
        for (int f0 = 0; f0 < HH; f0 += 32) {
            const int step = f0 >> 5;
            bf16x8 a0 = *(const bf16x8*)(mf + lane15 * RFP + f0 + quad * 8);
#pragma unroll
            for (int nt = 0; nt < 4; ++nt) {
                bf16x8 bf = *(const bf16x8*)(Wf1P + (size_t)(nt * 16 + step) * 512 + ln * 8);
                acc[nt] = __builtin_amdgcn_mfma_f32_16x16x32_bf16(a0, bf, acc[nt], 0, 0, 0);
            }
        }
        const float b2 = bf2v[0];
#pragma unroll
        for (int reg = 0; reg < 4; ++reg) {
            float s = 0.f;
#pragma unroll
            for (int nt = 0; nt < 4; ++nt) {
                const int n = nt * 16 + lane15;
                s = fmaf(fmaxf(acc[nt][reg] + bf1[n], 0.f), Wf2[n], s);
            }
#pragma unroll
            for (int off = 1; off < 16; off <<= 1) s += __shfl_xor(s, off);
            if (lane15 == 0)
                conf_out[(b0 + quad * 4 + reg) * KK + k] = s + b2;
        }
    }
}

// ---------------- k_ef: per (b,k) block, 8 waves, packed-B, 2 blocks/CU.
// Phase E batches 4 rows per group so the 8 LN butterfly chains (4 rows x {s,s2})
// interleave -> ds_bpermute latency hidden by ILP instead of exposed serially. ----------------
__launch_bounds__(512, 4)
__global__ void k_ef(
    const unsigned short* __restrict__ attn, const unsigned short* __restrict__ coarse_ws,
    const float* __restrict__ Wt,  const float* __restrict__ bt,
    const float* __restrict__ lng, const float* __restrict__ lnb,
    const unsigned short* __restrict__ Wr1P, const float* __restrict__ br1,
    const float* __restrict__ Wr2, const float* __restrict__ br2,
    float* __restrict__ pred_out,
    const float* __restrict__ conf, float* __restrict__ probs)
{
    __shared__ __align__(16) unsigned short rf[64 * RFP];  // 66,560 B
    __shared__ float coarse[TO];                           // 480 B
    __shared__ float br1s[HH];                             // 2,048 B
    __shared__ float2 wr2s[HH];                            // 4,096 B
    __shared__ float po2[8][64][2];                        // 4,096 B
    // total 77,280 B -> 2 blocks/CU

    const int tid = threadIdx.x;
    const int b = blockIdx.x / KK;
    const int k = blockIdx.x % KK;
    const int w = tid >> 6;          // 0..7
    const int ln = tid & 63;
    const int lane31 = ln & 31;
    const int hf = ln >> 5;
    const int cbase = ln * 8;

    const unsigned short* attb = attn + b * HH;

    if (tid < TO) coarse[tid] = bf2f(coarse_ws[(b * KK + k) * TO + tid]);
    br1s[tid] = br1[k * HH + tid];
    wr2s[tid] = ((const float2*)Wr2)[(size_t)k * HH + tid];

    // fold mode_probs softmax into k==0 blocks (conf ready: k_bcg completed)
    if (k == 0 && tid == 448) {
        float v[KK]; float m = -1e30f;
#pragma unroll
        for (int i = 0; i < KK; ++i) { v[i] = conf[b * KK + i]; m = fmaxf(m, v[i]); }
        float s = 0.f;
#pragma unroll
        for (int i = 0; i < KK; ++i) { v[i] = __expf(v[i] - m); s += v[i]; }
        float inv = 1.0f / s;
#pragma unroll
        for (int i = 0; i < KK; ++i) probs[b * KK + i] = v[i] * inv;
    }
    __syncthreads();

    // ---- Phase E: traj=gelu(coarse@Wt+bt); rf = LN(traj+attn)*g+b (bf16) ----
    // 4-row groups: compute x for 4 rows, then run 8 independent butterfly chains
    // together (ILP over the dependent ds_bpermute ladder), then apply+store.
    {
        F8 w0 = load8f(Wt + cbase);
        F8 w1 = load8f(Wt + HH + cbase);
        F8 b8 = load8f(bt + cbase);
        F8 g8 = load8f(lng + cbase);
        F8 bb8 = load8f(lnb + cbase);
        F8 a8 = load8b(attb + cbase);
#pragma unroll
        for (int g = 0; g < 2; ++g) {
            float x[4][8];
            float s[4], s2[4];
#pragma unroll
            for (int r = 0; r < 4; ++r) {
                const int t = w + 8 * (g * 4 + r);
                float ss = 0.f, ss2 = 0.f;
                if (t < 60) {
                    const float co0 = coarse[2 * t], co1 = coarse[2 * t + 1];
#pragma unroll
                    for (int j = 0; j < 8; ++j) {
                        float vv = fmaf(co0, w0.v[j], fmaf(co1, w1.v[j], b8.v[j]));
                        vv = gelu_cheap(vv) + a8.v[j];
                        x[r][j] = vv; ss += vv; ss2 = fmaf(vv, vv, ss2);
                    }
                } else {
#pragma unroll
                    for (int j = 0; j < 8; ++j) x[r][j] = 0.f;
                }
                s[r] = ss; s2[r] = ss2;
            }
            // batched butterflies: 8 independent chains pipeline the ds latency
#pragma unroll
            for (int off = 32; off > 0; off >>= 1) {
#pragma unroll
                for (int r = 0; r < 4; ++r) {
                    s[r] += __shfl_xor(s[r], off);
                    s2[r] += __shfl_xor(s2[r], off);
                }
            }
#pragma unroll
            for (int r = 0; r < 4; ++r) {
                const int t = w + 8 * (g * 4 + r);
                if (t < 60) {
                    float mean = s[r] * (1.0f / HH);
                    float var = fmaf(-mean, mean, s2[r] * (1.0f / HH));
                    float inv = rsqrtf(var + 1e-5f);
                    unsigned int pk[4];
#pragma unroll
                    for (int j = 0; j < 4; ++j) {
                        float y0 = fmaf((x[r][2 * j] - mean) * inv, g8.v[2 * j], bb8.v[2 * j]);
                        float y1 = fmaf((x[r][2 * j + 1] - mean) * inv, g8.v[2 * j + 1], bb8.v[2 * j + 1]);
                        pk[j] = pack2bf(y0, y1);
                    }
                    *(uint4*)(rf + t * RFP + cbase) = make_uint4(pk[0], pk[1], pk[2], pk[3]);
                } else {
                    *(uint4*)(rf + t * RFP + cbase) = make_uint4(0, 0, 0, 0);
                }
            }
        }
    }
    __syncthreads();

    // ---- Phase F: r=gelu(rf@Wr1+br1); offsets=r@Wr2 (32x32x16 MFMA, swapped operands,
    //      packed-B records [nch=16][step=32][512]; wave w owns nch 2w, 2w+1) ----
    {
        const unsigned short* bp0 = Wr1P + (size_t)k * (16 * 32 * 512)
                                  + (size_t)(w * 2) * 32 * 512 + ln * 8;
        const unsigned short* bp1 = bp0 + 32 * 512;   // next nch
        const int n0 = w * 64;
        const unsigned short* a0p = rf + lane31 * RFP + hf * 8;
        const unsigned short* a1p = a0p + 32 * RFP;

        f32x16 acc00 = {0.f,0.f,0.f,0.f,0.f,0.f,0.f,0.f,0.f,0.f,0.f,0.f,0.f,0.f,0.f,0.f};
        f32x16 acc01 = acc00, acc10 = acc00, acc11 = acc00;

        __builtin_amdgcn_s_setprio(1);
#pragma unroll
        for (int st = 0; st < 32; ++st) {
            const int k0 = st * 16;
            bf16x8 A0 = *(const bf16x8*)(a0p + k0);
            bf16x8 A1 = *(const bf16x8*)(a1p + k0);
            bf16x8 B0 = *(const bf16x8*)(bp0 + st * 512);
            bf16x8 B1 = *(const bf16x8*)(bp1 + st * 512);
            acc00 = __builtin_amdgcn_mfma_f32_32x32x16_bf16(B0, A0, acc00, 0, 0, 0);
            acc01 = __builtin_amdgcn_mfma_f32_32x32x16_bf16(B1, A0, acc01, 0, 0, 0);
            acc10 = __builtin_amdgcn_mfma_f32_32x32x16_bf16(B0, A1, acc10, 0, 0, 0);
            acc11 = __builtin_amdgcn_mfma_f32_32x32x16_bf16(B1, A1, acc11, 0, 0, 0);
        }
        __builtin_amdgcn_s_setprio(0);

        // In-lane contraction over n (regs); lane = m (time-step).
        float p00 = 0.f, p01 = 0.f, p10 = 0.f, p11 = 0.f;  // [m-half][o]
#pragma unroll
        for (int nt = 0; nt < 2; ++nt) {
#pragma unroll
            for (int reg = 0; reg < 16; ++reg) {
                const int n = n0 + nt * 32 + (reg & 3) + 8 * (reg >> 2) + 4 * hf;
                const float bb = br1s[n];
                const float2 w2 = wr2s[n];
                const float a0v = nt ? acc01[reg] : acc00[reg];
                const float a1v = nt ? acc11[reg] : acc10[reg];
                const float rv0 = gelu_cheap(a0v + bb);
                const float rv1 = gelu_cheap(a1v + bb);
                p00 = fmaf(rv0, w2.x, p00);
                p01 = fmaf(rv0, w2.y, p01);
                p10 = fmaf(rv1, w2.x, p10);
                p11 = fmaf(rv1, w2.y, p11);
            }
        }
        p00 += __shfl_xor(p00, 32);
        p01 += __shfl_xor(p01, 32);
        p10 += __shfl_xor(p10, 32);
        p11 += __shfl_xor(p11, 32);
        if (ln < 32) {
            *(float2*)&po2[w][lane31][0]      = make_float2(p00, p01);
            *(float2*)&po2[w][32 + lane31][0] = make_float2(p10, p11);
        }
    }
    __syncthreads();

    if (tid < TO) {
        int t = tid >> 1, o = tid & 1;
        float s = 0.f;
#pragma unroll
        for (int ww = 0; ww < 8; ++ww) s += po2[ww][t][o];
        pred_out[((b * KK + k) * TT + t) * 2 + o] = coarse[tid] + s + br2[k * 2 + o];
    }
}

extern "C" void kernel_launch(void* const* d_in, const int* in_sizes, int n_in,
                              void* d_out, int out_size, void* d_ws, size_t ws_size,
                              hipStream_t stream) {
    const float* I0  = (const float*)d_in[0];
    const float* I1  = (const float*)d_in[1];
    const float* I2  = (const float*)d_in[2];
    const float* MQ  = (const float*)d_in[3];
    const float* Wc1 = (const float*)d_in[4];
    const float* bc1 = (const float*)d_in[5];
    const float* Wc2 = (const float*)d_in[6];
    const float* bc2 = (const float*)d_in[7];
    const float* Wk1 = (const float*)d_in[8];
    const float* bk1 = (const float*)d_in[9];
    const float* Wk2 = (const float*)d_in[10];
    const float* bk2 = (const float*)d_in[11];
    const float* Wt  = (const float*)d_in[12];
    const float* bt  = (const float*)d_in[13];
    const float* Wv  = (const float*)d_in[18];
    const float* bv  = (const float*)d_in[19];
    const float* Wo  = (const float*)d_in[20];
    const float* bo  = (const float*)d_in[21];
    const float* lng = (const float*)d_in[22];
    const float* lnb = (const float*)d_in[23];
    const float* Wr1 = (const float*)d_in[24];
    const float* br1 = (const float*)d_in[25];
    const float* Wr2 = (const float*)d_in[26];
    const float* br2 = (const float*)d_in[27];
    const float* Wf1 = (const float*)d_in[28];
    const float* bf1 = (const float*)d_in[29];
    const float* Wf2 = (const float*)d_in[30];
    const float* bf2v = (const float*)d_in[31];

    // workspace layout (bf16 elems)
    unsigned short* wsu   = (unsigned short*)d_ws;
    unsigned short* wc1p  = wsu;                 //   786,432  (32nch x 48st x 512)
    unsigned short* wc2p  = wsu + 786432;        //   262,144
    unsigned short* wvp   = wsu + 1048576;       //   262,144
    unsigned short* wop   = wsu + 1310720;       //   262,144
    unsigned short* wk1p  = wsu + 1572864;       // 3,145,728  (K x 64nch x 16st x 512)
    unsigned short* wk2p  = wsu + 4718592;       //   786,432  (K x 8nch x 32st x 512, clamped)
    unsigned short* wf1p  = wsu + 5505024;       //    32,768  (4nch x 16st x 512)
    unsigned short* wr1p  = wsu + 5537792;       // 1,572,864  (K x 16nch x 32st x 512)
    unsigned short* ctx   = wsu + 7110656;       //   262,144
    unsigned short* attn  = wsu + 7372800;       //   262,144
    unsigned short* tmp   = wsu + 7634944;       //   262,144
    unsigned short* coarse= wsu + 7897088;       //   368,640
    float* conf = (float*)(wsu + 8265728);       //     3,072 fp32

    float* pred = (float*)d_out;
    float* probs = pred + BB * KK * TT * OO;

    // -- prep: all GEMM B-weights -> bf16 fragment-order records, one launch --
    PK8 pk;
    pk.e[0] = {Wc1, wc1p, 3 * HH, HH, 16, 32, 48, 1};   // 1536 recs
    pk.e[1] = {Wc2, wc2p, HH, HH, 16, 32, 16, 1};       //  512
    pk.e[2] = {Wv,  wvp,  HH, HH, 16, 32, 16, 1};       //  512
    pk.e[3] = {Wo,  wop,  HH, HH, 16, 32, 16, 1};       //  512
    pk.e[4] = {Wk1, wk1p, HH, H2, 16, 64, 16, KK};      // 6144
    pk.e[5] = {Wk2, wk2p, H2, TO, 16, 8, 32, KK};       // 1536 (clamped cols)
    pk.e[6] = {Wf1, wf1p, HH, 64, 16, 4, 16, 1};        //   64
    pk.e[7] = {Wr1, wr1p, HH, HH, 32, 16, 32, KK};      // 3072
    k_pack<<<dim3(3472), 256, 0, stream>>>(pk);

    // -- ctx chain (g1, g2 at full-GPU grid 16x16) --
    k_gemm_m<true,  true ><<<dim3(16, 16), 256, 0, stream>>>(I0, I1, I2, wc1p, bc1, tmp, 3 * HH);
    k_gemm_m<false, false><<<dim3(16, 16), 256, 0, stream>>>(tmp, nullptr, nullptr, wc2p, bc2, ctx, HH);

    // -- fused: k_bc (blocks 0..191) + v = ctx@Wv+bv (blocks 192..319) --
    k_bcg<<<dim3(320), 512, 0, stream>>>(ctx, MQ, wk1p, bk1, wk2p, bk2, wf1p, bf1, Wf2, bf2v,
                                         coarse, conf, wvp, bv, tmp);

    // -- attn = v @ Wo + bo --
    k_gemm_m<false, false><<<dim3(16, 16), 256, 0, stream>>>(tmp, nullptr, nullptr, wop, bo, attn, HH);

    // -- refine + predictions (+ folded softmax in k==0 blocks) --
    k_ef<<<dim3(BB * KK), 512, 0, stream>>>(attn, coarse, Wt, bt, lng, lnb,
                                            wr1p, br1, Wr2, br2, pred, conf, probs);
}